// Round 6
// baseline (261.947 us; speedup 1.0000x reference)
//
#include <hip/hip_runtime.h>

constexpr int Bb = 4;
constexpr int Ss = 2048;
constexpr int QSTR = 1536;   // combined qkv row stride (g 0..767, t 768..1535)

typedef __bf16 bf16x8 __attribute__((ext_vector_type(8)));
typedef __bf16 bf16x4 __attribute__((ext_vector_type(4)));
typedef float  f32x4  __attribute__((ext_vector_type(4)));
typedef unsigned int uint2v __attribute__((ext_vector_type(2)));
typedef unsigned int uint4v __attribute__((ext_vector_type(4)));

// async global->LDS, 16B per lane; dest = wave-uniform base + lane*16
__device__ __forceinline__ void glds16(const void* g, void* l) {
    __builtin_amdgcn_global_load_lds(
        (const __attribute__((address_space(1))) unsigned int*)g,
        (__attribute__((address_space(3))) unsigned int*)l, 16, 0, 0);
}

// 4x4 lane-group transpose step across lanes {q, q+16, q+32, q+48}:
// pure VALU: permlane32_swap + permlane16_swap. (Harness-verified in attn.)
__device__ __forceinline__ void xpose4(unsigned int& a, unsigned int& b) {
    uint2v r = __builtin_amdgcn_permlane32_swap(a, b, false, false);
    uint2v u = __builtin_amdgcn_permlane16_swap(r[0], r[1], false, false);
    a = u[0]; b = u[1];
}

// packed f32 pair -> 2 bf16 in one u32 (single v_cvt_pk_bf16_f32)
__device__ __forceinline__ unsigned int cvtpk(float a, float b) {
    unsigned int r;
    asm("v_cvt_pk_bf16_f32 %0, %1, %2" : "=v"(r) : "v"(a), "v"(b));
    return r;
}

// exp2 pair -> packed bf16 (attn softmax path)
__device__ __forceinline__ unsigned int exp2_pk(float a, float b) {
    float ea = __builtin_amdgcn_exp2f(a);
    float eb = __builtin_amdgcn_exp2f(b);
    return cvtpk(ea, eb);
}

// Two D-layout tiles (feature=quad*4+r in regs, token=lane&15) -> one MFMA
// operand chunk (token=lane&15, feature k=quad*8+j). (Verified in attn/R5.)
__device__ __forceinline__ bf16x8 pack_pair(f32x4 dA, f32x4 dB) {
    unsigned int RA0 = cvtpk(dA[0], dA[1]);
    unsigned int RA1 = cvtpk(dA[2], dA[3]);
    unsigned int RB0 = cvtpk(dB[0], dB[1]);
    unsigned int RB1 = cvtpk(dB[2], dB[3]);
    xpose4(RA0, RB0);
    xpose4(RA1, RB1);
    uint4v u = {RA0, RA1, RB0, RB1};
    return __builtin_bit_cast(bf16x8, u);
}

// 4 output-feature tiles x K: acc[i] = sum_k W[(ft0+i)*16+qrow][k] * act[tok][k]
template<int NK>
__device__ __forceinline__ void mm4(
    const __bf16* __restrict__ W, const int K, const int ft0,
    const bf16x8* act, const int qrow, const int quad, f32x4 acc[4])
{
#pragma unroll
    for (int i = 0; i < 4; i++) acc[i] = {0.f, 0.f, 0.f, 0.f};
#pragma unroll
    for (int kc = 0; kc < NK; kc++) {
        bf16x8 wf[4];
#pragma unroll
        for (int i = 0; i < 4; i++)
            wf[i] = *(const bf16x8*)&W[(size_t)((ft0 + i) * 16 + qrow) * K + kc * 32 + quad * 8];
#pragma unroll
        for (int i = 0; i < 4; i++)
            acc[i] = __builtin_amdgcn_mfma_f32_16x16x32_bf16(wf[i], act[kc], acc[i], 0, 0, 0);
    }
}

template<int NK, bool SILU>
__device__ __forceinline__ void stage_pack4(
    const __bf16* __restrict__ W, const int K, const int ft0,
    const float* __restrict__ bias,
    const bf16x8* act, const int qrow, const int quad, bf16x8* outc)
{
    f32x4 acc[4];
    mm4<NK>(W, K, ft0, act, qrow, quad, acc);
#pragma unroll
    for (int i = 0; i < 4; i++) {
        float4 bz = *(const float4*)&bias[(ft0 + i) * 16 + quad * 4];
        acc[i][0] += bz.x; acc[i][1] += bz.y; acc[i][2] += bz.z; acc[i][3] += bz.w;
        if (SILU) {
#pragma unroll
            for (int r = 0; r < 4; r++) {
                float v = acc[i][r];
                acc[i][r] = v / (1.f + __builtin_amdgcn_exp2f(-v * 1.4426950408889634f));
            }
        }
    }
    outc[0] = pack_pair(acc[0], acc[1]);
    outc[1] = pack_pair(acc[2], acc[3]);
}

template<int NK>
__device__ __forceinline__ void stage_d4(
    const __bf16* __restrict__ W, const int K, const int ft0,
    const float* __restrict__ bias,
    const bf16x8* act, const int qrow, const int quad, f32x4* dout)
{
    f32x4 acc[4];
    mm4<NK>(W, K, ft0, act, qrow, quad, acc);
#pragma unroll
    for (int i = 0; i < 4; i++) {
        float4 bz = *(const float4*)&bias[(ft0 + i) * 16 + quad * 4];
        dout[i][0] = acc[i][0] + bz.x;
        dout[i][1] = acc[i][1] + bz.y;
        dout[i][2] = acc[i][2] + bz.z;
        dout[i][3] = acc[i][3] + bz.w;
    }
}

// ---------------------------------------------------------------------------
// convert_all: fp32 -> bf16 for x and the 8 weight matrices, one launch.
// ---------------------------------------------------------------------------
struct CvtArgs {
    const float* src[9];
    __bf16* dst[9];
    int start[10];
};

__global__ __launch_bounds__(256) void convert_all(CvtArgs a)
{
    int e = 0;
    const int bid = blockIdx.x;
#pragma unroll
    for (int i = 0; i < 8; i++) if (bid >= a.start[i + 1]) e = i + 1;
    const int idx = (bid - a.start[e]) * 256 + threadIdx.x;
    const float* s = a.src[e];
    float4 v0 = *(const float4*)&s[(size_t)idx * 8];
    float4 v1 = *(const float4*)&s[(size_t)idx * 8 + 4];
    bf16x8 o;
    o[0] = (__bf16)v0.x; o[1] = (__bf16)v0.y; o[2] = (__bf16)v0.z; o[3] = (__bf16)v0.w;
    o[4] = (__bf16)v1.x; o[5] = (__bf16)v1.y; o[6] = (__bf16)v1.z; o[7] = (__bf16)v1.w;
    *(bf16x8*)&a.dst[e][(size_t)idx * 8] = o;
}

// ---------------------------------------------------------------------------
// gemm128: BM=BN=128, BK=64; 4 waves each 64x64 (4x4 MFMA accs). For QKV.
// XOR swizzle: LDS slot (row,g) holds global chunk (row, g^(row&7)).
// ---------------------------------------------------------------------------
__global__ __launch_bounds__(256) void gemm128(
    const __bf16* __restrict__ A, const __bf16* __restrict__ W,
    const float* __restrict__ bias, const float* __restrict__ bias2, int bsplit,
    __bf16* __restrict__ C, int K, int ldc)
{
    __shared__ __bf16 As[128 * 64];
    __shared__ __bf16 Ws[128 * 64];
    const int tid = threadIdx.x;
    const int lane = tid & 63;
    const int wv = tid >> 6;
    const int wm = (wv >> 1) * 64;
    const int wn = (wv & 1) * 64;
    const int qrow = lane & 15;
    const int quad = lane >> 4;
    const int n0 = blockIdx.x * 128;
    const int m0 = blockIdx.y * 128;

    f32x4 acc[4][4];
#pragma unroll
    for (int i = 0; i < 4; i++)
#pragma unroll
        for (int j = 0; j < 4; j++) acc[i][j] = {0.f, 0.f, 0.f, 0.f};

    for (int k0 = 0; k0 < K; k0 += 64) {
        __syncthreads();
#pragma unroll
        for (int i = 0; i < 4; i++) {
            const int c = (wv * 4 + i) * 64 + lane;
            const int row = c >> 3, g = c & 7;
            const int gs = (g ^ (row & 7)) * 8;
            glds16(&A[(size_t)(m0 + row) * K + k0 + gs], &As[(wv * 4 + i) * 512]);
            glds16(&W[(size_t)(n0 + row) * K + k0 + gs], &Ws[(wv * 4 + i) * 512]);
        }
        __syncthreads();
#pragma unroll
        for (int ksub = 0; ksub < 2; ksub++) {
            const int gl = ksub * 4 + quad;
            bf16x8 af[4], bf[4];
#pragma unroll
            for (int mi = 0; mi < 4; mi++) {
                const int row = wm + mi * 16 + qrow;
                af[mi] = *(const bf16x8*)&As[row * 64 + (gl ^ (row & 7)) * 8];
            }
#pragma unroll
            for (int ni = 0; ni < 4; ni++) {
                const int row = wn + ni * 16 + qrow;
                bf[ni] = *(const bf16x8*)&Ws[row * 64 + (gl ^ (row & 7)) * 8];
            }
#pragma unroll
            for (int mi = 0; mi < 4; mi++)
#pragma unroll
                for (int ni = 0; ni < 4; ni++)
                    acc[mi][ni] = __builtin_amdgcn_mfma_f32_16x16x32_bf16(
                        af[mi], bf[ni], acc[mi][ni], 0, 0, 0);
        }
    }

    float bz[4];
#pragma unroll
    for (int ni = 0; ni < 4; ni++) {
        const int n = n0 + wn + ni * 16 + qrow;
        bz[ni] = (n < bsplit) ? bias[n] : bias2[n - bsplit];
    }
#pragma unroll
    for (int mi = 0; mi < 4; mi++)
#pragma unroll
        for (int r = 0; r < 4; r++) {
            const int row = m0 + wm + mi * 16 + quad * 4 + r;
#pragma unroll
            for (int ni = 0; ni < 4; ni++) {
                float v = acc[mi][ni][r] + bz[ni];
                C[(size_t)row * ldc + n0 + wn + ni * 16 + qrow] = (__bf16)v;
            }
        }
}

// ---------------------------------------------------------------------------
// attn_fused: 512-thread blocks.
// Blocks 0..1023: global MHA split-K x4 partials. 8 waves x 2 q-tiles x 16 q
//   = 256 q/block, 8 key-chunks of 64 keys each. P never touches LDS
//   (permlane transpose). exp2+bf16-pack via v_exp_f32 + v_cvt_pk_bf16_f32.
// Blocks 1024..1535: local window-5 MHA -> acat cols 256-511.
// ---------------------------------------------------------------------------
__global__ __launch_bounds__(512) void attn_fused(
    const __bf16* __restrict__ qkv, __bf16* __restrict__ Op,
    float* __restrict__ Lp, __bf16* __restrict__ acat)
{
    __shared__ __bf16 Kl[2][64 * 32];
    __shared__ __bf16 Vt[2][32 * 72];

    const int t = threadIdx.x;
    const int lane = t & 63;
    const int wv = t >> 6;          // 0..7

    if (blockIdx.x < 1024) {
        const int bid = blockIdx.x;
        const int sp = bid & 3;          // split-K x4
        const int qc = (bid >> 2) & 7;   // 8 chunks of 256 q
        const int h  = (bid >> 5) & 7;
        const int b  = bid >> 8;
        const int bS = b * Ss;
        const int q0 = qc * 256;

        const int qrow = lane & 15;
        const int quad = lane >> 4;
        const float cQ = 1.4426950408889634f * 0.17677669529663687f; // log2e/sqrt(32)

        bf16x8 qf[2];
#pragma unroll
        for (int tl = 0; tl < 2; tl++) {
            bf16x8 qraw = *(const bf16x8*)(qkv +
                (size_t)(bS + q0 + wv * 32 + tl * 16 + qrow) * QSTR + h * 32 + quad * 8);
#pragma unroll
            for (int i = 0; i < 8; i++) qf[tl][i] = (__bf16)((float)qraw[i] * cQ);
        }
        bf16x8 ones;
#pragma unroll
        for (int i = 0; i < 8; i++) ones[i] = (__bf16)1.0f;

        f32x4 o0[2], o1[2], lac[2];
#pragma unroll
        for (int tl = 0; tl < 2; tl++) {
            o0[tl] = {0.f, 0.f, 0.f, 0.f};
            o1[tl] = {0.f, 0.f, 0.f, 0.f};
            lac[tl] = {0.f, 0.f, 0.f, 0.f};
        }
        const f32x4 z = {0.f, 0.f, 0.f, 0.f};

        const int kc_c = wv * 64 + lane;
        const int kkey = kc_c >> 2, kdg = kc_c & 3;
        const int vkey = t & 63, vq = t >> 6;   // V: key, dim group of 4
        const int kc0 = sp * 8;                 // 8 chunks per split

        // prologue: prefetch chunk 0 (V into regs, K via glds into Kl[0])
        bf16x4 vreg = *(const bf16x4*)(qkv +
            (size_t)(bS + kc0 * 64 + vkey) * QSTR + 512 + h * 32 + vq * 4);
        if (wv < 4)
            glds16(qkv + (size_t)(bS + kc0 * 64 + kkey) * QSTR + 256 + h * 32 + kdg * 8,
                   &Kl[0][wv * 512]);

        for (int i = 0; i < 8; i++) {
            const int cur = i & 1;
#pragma unroll
            for (int e = 0; e < 4; e++) Vt[cur][(vq * 4 + e) * 72 + vkey] = vreg[e];
            __syncthreads();
            const int nx = (i < 7) ? (kc0 + i + 1) : (kc0 + 7);
            vreg = *(const bf16x4*)(qkv +
                (size_t)(bS + nx * 64 + vkey) * QSTR + 512 + h * 32 + vq * 4);
            if (i < 7 && wv < 4)
                glds16(qkv + (size_t)(bS + nx * 64 + kkey) * QSTR + 256 + h * 32 + kdg * 8,
                       &Kl[1 - cur][wv * 512]);

            // shared K/V fragments, read once, used by both q-tiles
            bf16x8 kf[4];
#pragma unroll
            for (int kg = 0; kg < 4; kg++)
                kf[kg] = *(const bf16x8*)&Kl[cur][(kg * 16 + qrow) * 32 + quad * 8];
            bf16x8 vf00 = *(const bf16x8*)&Vt[cur][qrow * 72 + quad * 8];
            bf16x8 vf01 = *(const bf16x8*)&Vt[cur][qrow * 72 + 32 + quad * 8];
            bf16x8 vf10 = *(const bf16x8*)&Vt[cur][(16 + qrow) * 72 + quad * 8];
            bf16x8 vf11 = *(const bf16x8*)&Vt[cur][(16 + qrow) * 72 + 32 + quad * 8];

#pragma unroll
            for (int tl = 0; tl < 2; tl++) {
                f32x4 s[4];
#pragma unroll
                for (int kg = 0; kg < 4; kg++)
                    s[kg] = __builtin_amdgcn_mfma_f32_16x16x32_bf16(
                        kf[kg], qf[tl], z, 0, 0, 0);
                unsigned int R[4][2];
#pragma unroll
                for (int kg = 0; kg < 4; kg++) {
                    R[kg][0] = exp2_pk(s[kg][0], s[kg][1]);
                    R[kg][1] = exp2_pk(s[kg][2], s[kg][3]);
                }
                xpose4(R[0][0], R[1][0]);
                xpose4(R[0][1], R[1][1]);
                xpose4(R[2][0], R[3][0]);
                xpose4(R[2][1], R[3][1]);
                uint4v p0u = {R[0][0], R[0][1], R[1][0], R[1][1]};
                uint4v p1u = {R[2][0], R[2][1], R[3][0], R[3][1]};
                bf16x8 pf0 = __builtin_bit_cast(bf16x8, p0u);
                bf16x8 pf1 = __builtin_bit_cast(bf16x8, p1u);

                o0[tl] = __builtin_amdgcn_mfma_f32_16x16x32_bf16(vf00, pf0, o0[tl], 0, 0, 0);
                o1[tl] = __builtin_amdgcn_mfma_f32_16x16x32_bf16(vf10, pf0, o1[tl], 0, 0, 0);
                lac[tl] = __builtin_amdgcn_mfma_f32_16x16x32_bf16(ones, pf0, lac[tl], 0, 0, 0);
                o0[tl] = __builtin_amdgcn_mfma_f32_16x16x32_bf16(vf01, pf1, o0[tl], 0, 0, 0);
                o1[tl] = __builtin_amdgcn_mfma_f32_16x16x32_bf16(vf11, pf1, o1[tl], 0, 0, 0);
                lac[tl] = __builtin_amdgcn_mfma_f32_16x16x32_bf16(ones, pf1, lac[tl], 0, 0, 0);
            }
        }

#pragma unroll
        for (int tl = 0; tl < 2; tl++) {
            const int gid = (b * 8 + h) * 2048 + q0 + wv * 32 + tl * 16 + qrow;
            __bf16* po = Op + (size_t)sp * 2097152 + (size_t)gid * 32;
            bf16x4 w0, w1;
#pragma unroll
            for (int r = 0; r < 4; r++) {
                w0[r] = (__bf16)o0[tl][r];
                w1[r] = (__bf16)o1[tl][r];
            }
            *(bf16x4*)&po[quad * 4]      = w0;
            *(bf16x4*)&po[16 + quad * 4] = w1;
            if (quad == 0) Lp[sp * 65536 + gid] = lac[tl][0];
        }
    } else {
        // local window-5 attention: 8 lanes per (b,s,h) row, 8 rows per wave
        const int w = (blockIdx.x - 1024) * 8 + wv;  // 0..4095
        const int g = lane >> 3;                      // row-in-wave 0..7
        const int l8 = lane & 7;                      // dim-group (8 bf16)
        const int R = w * 8 + g;                      // 0..32767
        const int h = R & 3;
        const int s = (R >> 2) & 2047;
        const int b = R >> 13;

        float qv[8];
        {
            bf16x8 q8 = *(const bf16x8*)&qkv[(size_t)(b * Ss + s) * QSTR + 768 + h * 64 + l8 * 8];
#pragma unroll
            for (int e = 0; e < 8; e++) qv[e] = (float)q8[e];
        }

        float sc[5];
        bf16x8 v8[5];
#pragma unroll
        for (int j = 0; j < 5; j++) {
            int pos = s + j - 2;
            bool valid = (pos >= 0) && (pos < Ss);
            int cpos = valid ? pos : 0;
            const size_t rb = (size_t)(b * Ss + cpos) * QSTR;
            bf16x8 k8 = *(const bf16x8*)&qkv[rb + 1024 + h * 64 + l8 * 8];
            v8[j]     = *(const bf16x8*)&qkv[rb + 1280 + h * 64 + l8 * 8];
            float p = 0.f;
#pragma unroll
            for (int e = 0; e < 8; e++) p += qv[e] * (float)k8[e];
            p += __shfl_xor(p, 1, 64);
            p += __shfl_xor(p, 2, 64);
            p += __shfl_xor(p, 4, 64);
            sc[j] = valid ? p * 0.125f : -1e30f;
        }
        float m = sc[0];
#pragma unroll
        for (int j = 1; j < 5; j++) m = fmaxf(m, sc[j]);
        float l = 0.f;
        float o[8];
#pragma unroll
        for (int e = 0; e < 8; e++) o[e] = 0.f;
#pragma unroll
        for (int j = 0; j < 5; j++) {
            float pe = __builtin_amdgcn_exp2f((sc[j] - m) * 1.4426950408889634f);
            l += pe;
#pragma unroll
            for (int e = 0; e < 8; e++) o[e] += pe * (float)v8[j][e];
        }
        const float li = 1.f / l;
        bf16x8 r;
#pragma unroll
        for (int e = 0; e < 8; e++) r[e] = (__bf16)(o[e] * li);
        *(bf16x8*)&acat[(size_t)(b * Ss + s) * 512 + 256 + h * 64 + l8 * 8] = r;
    }
}

// ---------------------------------------------------------------------------
// epilogue: ONE kernel for combine + out-proj + fusion-MLP + LN1 + FFN + LN2.
// 512 blocks x 256 threads (4 waves). Each BLOCK owns 16 tokens; the 4 waves
// split every stage's OUTPUT features 4-ways (disjoint weight rows), then
// exchange quarter-results through a double-buffered 16-slot LDS buffer
// (16B/lane/slot, one barrier per stage). LN sums computed redundantly per
// wave after an fp32 exchange. Same per-stage math as the R5 kernel
// (numerically verified); redistribution fixes the 2-waves/CU latency bind:
// now 2048 waves = 8/CU, each with 1/4 the serial chain.
// ---------------------------------------------------------------------------
__global__ __launch_bounds__(256) void epilogue(
    const __bf16* __restrict__ Op, const float* __restrict__ Lp,
    const __bf16* __restrict__ acat, const float* __restrict__ x,
    const __bf16* __restrict__ w_gout, const float* __restrict__ g_out_b,
    const __bf16* __restrict__ w_tout, const float* __restrict__ t_out_b,
    const __bf16* __restrict__ w_f1, const float* __restrict__ fus_b1,
    const __bf16* __restrict__ w_f2, const float* __restrict__ fus_b2,
    const __bf16* __restrict__ w_n1, const float* __restrict__ ffn_b1,
    const __bf16* __restrict__ w_n2, const float* __restrict__ ffn_b2,
    const float* __restrict__ gn_g, const float* __restrict__ gn_b,
    const float* __restrict__ fn_g, const float* __restrict__ fn_b,
    float* __restrict__ out)
{
    __shared__ __bf16 ex[2][16 * 64 * 8];   // [buf][slot*64+lane] 16B units
    const int tid = threadIdx.x;
    const int lane = tid & 63;
    const int wv = tid >> 6;                // 0..3
    const int qrow = lane & 15;
    const int quad = lane >> 4;
    const int t = blockIdx.x * 16 + qrow;   // token 0..8191
    const int b = t >> 11;
    const int q = t & 2047;

#define SLOT(buf, slot) ((bf16x8*)&ex[buf][((slot) * 64 + lane) * 8])

    // ---- S0: assemble acat operand chunks (split across waves) ----
#pragma unroll
    for (int e = 0; e < 2; e++) {
        const int h = wv * 2 + e;
        const size_t gid = (size_t)(b * 8 + h) * 2048 + q;
        const float li = 1.f / (Lp[gid] + Lp[65536 + gid] +
                                Lp[131072 + gid] + Lp[196608 + gid]);
        const __bf16* base = Op + gid * 32 + quad * 8;
        bf16x8 a0 = *(const bf16x8*)&base[0];
        bf16x8 a1 = *(const bf16x8*)&base[2097152];
        bf16x8 a2 = *(const bf16x8*)&base[4194304];
        bf16x8 a3 = *(const bf16x8*)&base[6291456];
        unsigned int w[4];
#pragma unroll
        for (int p = 0; p < 4; p++) {
            float v0 = ((float)a0[2*p]   + (float)a1[2*p]   +
                        (float)a2[2*p]   + (float)a3[2*p])   * li;
            float v1 = ((float)a0[2*p+1] + (float)a1[2*p+1] +
                        (float)a2[2*p+1] + (float)a3[2*p+1]) * li;
            w[p] = cvtpk(v0, v1);
        }
        uint4v u = {w[0], w[1], w[2], w[3]};
        *SLOT(0, h) = __builtin_bit_cast(bf16x8, u);
        *SLOT(0, 8 + h) = *(const bf16x8*)&acat[(size_t)t * 512 + 256 + h * 32 + quad * 8];
    }
    __syncthreads();
    bf16x8 act[16];
#pragma unroll
    for (int c = 0; c < 16; c++) act[c] = *SLOT(0, c);

    // ---- S1: fcomb = [act[0:8]*w_gout^T+gb | act[8:16]*w_tout^T+tb] ----
    bf16x8 oc[4];
    if (wv < 2) {
        stage_pack4<8, false>(w_gout, 256, wv * 8,     g_out_b, act, qrow, quad, &oc[0]);
        stage_pack4<8, false>(w_gout, 256, wv * 8 + 4, g_out_b, act, qrow, quad, &oc[2]);
    } else {
        stage_pack4<8, false>(w_tout, 256, (wv - 2) * 8,     t_out_b, act + 8, qrow, quad, &oc[0]);
        stage_pack4<8, false>(w_tout, 256, (wv - 2) * 8 + 4, t_out_b, act + 8, qrow, quad, &oc[2]);
    }
#pragma unroll
    for (int i = 0; i < 4; i++) *SLOT(1, wv * 4 + i) = oc[i];
    __syncthreads();
#pragma unroll
    for (int c = 0; c < 16; c++) act[c] = *SLOT(1, c);

    // ---- S2: h1 = silu(fcomb * w_f1^T + fus_b1), K=512 N=512 ----
    stage_pack4<16, true>(w_f1, 512, wv * 8,     fus_b1, act, qrow, quad, &oc[0]);
    stage_pack4<16, true>(w_f1, 512, wv * 8 + 4, fus_b1, act, qrow, quad, &oc[2]);
#pragma unroll
    for (int i = 0; i < 4; i++) *SLOT(0, wv * 4 + i) = oc[i];
    __syncthreads();
#pragma unroll
    for (int c = 0; c < 16; c++) act[c] = *SLOT(0, c);

    // ---- S3: xfb = h1 * w_f2^T + fus_b2 (own quarter, fp32) + x residual ---
    f32x4 dp[4];
    stage_d4<16>(w_f2, 512, wv * 4, fus_b2, act, qrow, quad, dp);
#pragma unroll
    for (int i = 0; i < 4; i++) {
        float4 xr = *(const float4*)&x[(size_t)t * 256 + (wv * 4 + i) * 16 + quad * 4];
        dp[i][0] += xr.x; dp[i][1] += xr.y; dp[i][2] += xr.z; dp[i][3] += xr.w;
    }
#pragma unroll
    for (int i = 0; i < 4; i++) *(f32x4*)SLOT(1, wv * 4 + i) = dp[i];
    __syncthreads();
    f32x4 d[16];
#pragma unroll
    for (int ft = 0; ft < 16; ft++) d[ft] = *(f32x4*)SLOT(1, ft);

    // ---- LN1 (redundant per wave) ----
    float s = 0.f;
#pragma unroll
    for (int ft = 0; ft < 16; ft++) s += d[ft][0] + d[ft][1] + d[ft][2] + d[ft][3];
    s += __shfl_xor(s, 16, 64);
    s += __shfl_xor(s, 32, 64);
    const float mu = s * (1.f / 256.f);
    float sq = 0.f;
#pragma unroll
    for (int ft = 0; ft < 16; ft++)
#pragma unroll
        for (int r = 0; r < 4; r++) { d[ft][r] -= mu; sq += d[ft][r] * d[ft][r]; }
    sq += __shfl_xor(sq, 16, 64);
    sq += __shfl_xor(sq, 32, 64);
    const float rs = rsqrtf(sq * (1.f / 256.f) + 1e-5f);
#pragma unroll
    for (int ft = 0; ft < 16; ft++) {
        float4 gg = *(const float4*)&gn_g[ft * 16 + quad * 4];
        float4 bb = *(const float4*)&gn_b[ft * 16 + quad * 4];
        d[ft][0] = d[ft][0] * rs * gg.x + bb.x;
        d[ft][1] = d[ft][1] * rs * gg.y + bb.y;
        d[ft][2] = d[ft][2] * rs * gg.z + bb.z;
        d[ft][3] = d[ft][3] * rs * gg.w + bb.w;
    }
    bf16x8 actx2[8];
#pragma unroll
    for (int c = 0; c < 8; c++)
        actx2[c] = pack_pair(d[2 * c], d[2 * c + 1]);
    // own quarter of x2 (fp32) for the S5 residual; full d[] can die here
    f32x4 x2own[4];
#pragma unroll
    for (int i = 0; i < 4; i++) x2own[i] = d[wv * 4 + i];

    // ---- S4: h2 = silu(x2 * w_n1^T + ffn_b1), K=256 N=512 ----
    stage_pack4<8, true>(w_n1, 256, wv * 8,     ffn_b1, actx2, qrow, quad, &oc[0]);
    stage_pack4<8, true>(w_n1, 256, wv * 8 + 4, ffn_b1, actx2, qrow, quad, &oc[2]);
#pragma unroll
    for (int i = 0; i < 4; i++) *SLOT(0, wv * 4 + i) = oc[i];
    __syncthreads();
#pragma unroll
    for (int c = 0; c < 16; c++) act[c] = *SLOT(0, c);

    // ---- S5: xffb = h2 * w_n2^T + ffn_b2 (own quarter) + x2 residual ----
    stage_d4<16>(w_n2, 512, wv * 4, ffn_b2, act, qrow, quad, dp);
#pragma unroll
    for (int i = 0; i < 4; i++)
#pragma unroll
        for (int r = 0; r < 4; r++) dp[i][r] += x2own[i][r];
#pragma unroll
    for (int i = 0; i < 4; i++) *(f32x4*)SLOT(1, wv * 4 + i) = dp[i];
    __syncthreads();
#pragma unroll
    for (int ft = 0; ft < 16; ft++) d[ft] = *(f32x4*)SLOT(1, ft);

    // ---- LN2 (sums redundant; each wave writes its own quarter) ----
    float s2 = 0.f;
#pragma unroll
    for (int ft = 0; ft < 16; ft++) s2 += d[ft][0] + d[ft][1] + d[ft][2] + d[ft][3];
    s2 += __shfl_xor(s2, 16, 64);
    s2 += __shfl_xor(s2, 32, 64);
    const float mu2 = s2 * (1.f / 256.f);
    float sq2 = 0.f;
#pragma unroll
    for (int ft = 0; ft < 16; ft++)
#pragma unroll
        for (int r = 0; r < 4; r++) { d[ft][r] -= mu2; sq2 += d[ft][r] * d[ft][r]; }
    sq2 += __shfl_xor(sq2, 16, 64);
    sq2 += __shfl_xor(sq2, 32, 64);
    const float rs2 = rsqrtf(sq2 * (1.f / 256.f) + 1e-5f);
#pragma unroll
    for (int i = 0; i < 4; i++) {
        const int ft = wv * 4 + i;
        float4 gg = *(const float4*)&fn_g[ft * 16 + quad * 4];
        float4 bb = *(const float4*)&fn_b[ft * 16 + quad * 4];
        f32x4 o;
        o[0] = d[ft][0] * rs2 * gg.x + bb.x;
        o[1] = d[ft][1] * rs2 * gg.y + bb.y;
        o[2] = d[ft][2] * rs2 * gg.z + bb.z;
        o[3] = d[ft][3] * rs2 * gg.w + bb.w;
        *(f32x4*)&out[(size_t)t * 256 + ft * 16 + quad * 4] = o;
    }
#undef SLOT
}

// ---------------------------------------------------------------------------
extern "C" void kernel_launch(void* const* d_in, const int* in_sizes, int n_in,
                              void* d_out, int out_size, void* d_ws, size_t ws_size,
                              hipStream_t stream)
{
    const float* x      = (const float*)d_in[0];
    const float* g_in_w = (const float*)d_in[1];
    const float* g_in_b = (const float*)d_in[2];
    const float* g_out_w= (const float*)d_in[3];
    const float* g_out_b= (const float*)d_in[4];
    const float* t_in_w = (const float*)d_in[5];
    const float* t_in_b = (const float*)d_in[6];
    const float* t_out_w= (const float*)d_in[7];
    const float* t_out_b= (const float*)d_in[8];
    const float* fus_w1 = (const float*)d_in[9];
    const float* fus_b1 = (const float*)d_in[10];
    const float* fus_w2 = (const float*)d_in[11];
    const float* fus_b2 = (const float*)d_in[12];
    const float* ffn_w1 = (const float*)d_in[13];
    const float* ffn_b1 = (const float*)d_in[14];
    const float* ffn_w2 = (const float*)d_in[15];
    const float* ffn_b2 = (const float*)d_in[16];
    const float* gn_g   = (const float*)d_in[17];
    const float* gn_b   = (const float*)d_in[18];
    const float* fn_g   = (const float*)d_in[19];
    const float* fn_b   = (const float*)d_in[20];
    float* out = (float*)d_out;
    float* ws  = (float*)d_ws;

    // ws layout in f32 slots
    __bf16* xb     = (__bf16*)(ws);                 // [0, 1048576)
    __bf16* wb     = (__bf16*)(ws + 1048576);       // [1048576, 1638400)
    __bf16* qkvgl  = (__bf16*)(ws + 1638400);       // [1638400, 7929856)  8192x1536
    __bf16* acat   = (__bf16*)(ws + 7929856);       // [7929856, 10027008) 8192x512
    // attention partials: live only between attn_fused and epilogue.
    __bf16* Op = (__bf16*)(ws + 10027008);          // 4x65536x32 bf16
    float*  Lp = ws + 18415616;                     // 4x65536 fp32

    __bf16* w_gin  = wb;              // [1536x256] combined (g rows 0-767, t 768-1535)
    __bf16* w_gout = wb + 393216;
    __bf16* w_tout = wb + 458752;
    __bf16* w_f1   = wb + 524288;
    __bf16* w_f2   = wb + 786432;
    __bf16* w_n1   = wb + 917504;
    __bf16* w_n2   = wb + 1048576;

    CvtArgs ca;
    ca.src[0] = x;      ca.dst[0] = xb;
    ca.src[1] = g_in_w; ca.dst[1] = w_gin;
    ca.src[2] = t_in_w; ca.dst[2] = w_gin + 196608;
    ca.src[3] = g_out_w;ca.dst[3] = w_gout;
    ca.src[4] = t_out_w;ca.dst[4] = w_tout;
    ca.src[5] = fus_w1; ca.dst[5] = w_f1;
    ca.src[6] = fus_w2; ca.dst[6] = w_f2;
    ca.src[7] = ffn_w1; ca.dst[7] = w_n1;
    ca.src[8] = ffn_w2; ca.dst[8] = w_n2;
    int st[10] = {0, 1024, 1120, 1216, 1248, 1280, 1408, 1472, 1536, 1600};
    for (int i = 0; i < 10; i++) ca.start[i] = st[i];

    convert_all<<<dim3(1600), 256, 0, stream>>>(ca);

    // Combined QKV projection: M=8192, N=1536, K=256 -> qkvgl (128x128 tiles)
    gemm128<<<dim3(12, 64), 256, 0, stream>>>(
        xb, w_gin, g_in_b, t_in_b, 768, qkvgl, 256, QSTR);
    // Global attention partials split-K x4 (blocks 0-1023) + local (1024-1535)
    attn_fused<<<dim3(1536), 512, 0, stream>>>(qkvgl, Op, Lp, acat);
    // Everything else: one fused token-parallel kernel (4-way feature split)
    epilogue<<<dim3(512), 256, 0, stream>>>(
        Op, Lp, acat, x,
        w_gout, g_out_b, w_tout, t_out_b,
        w_f1, fus_b1, w_f2, fus_b2,
        w_n1, ffn_b1, w_n2, ffn_b2,
        gn_g, gn_b, fn_g, fn_b, out);
}

// Round 7
// 256.870 us; speedup vs baseline: 1.0198x; 1.0198x over previous
//
#include <hip/hip_runtime.h>

constexpr int Bb = 4;
constexpr int Ss = 2048;
constexpr int QSTR = 1536;   // combined qkv row stride (g 0..767, t 768..1535)

typedef __bf16 bf16x8 __attribute__((ext_vector_type(8)));
typedef __bf16 bf16x4 __attribute__((ext_vector_type(4)));
typedef float  f32x4  __attribute__((ext_vector_type(4)));
typedef unsigned int uint2v __attribute__((ext_vector_type(2)));
typedef unsigned int uint4v __attribute__((ext_vector_type(4)));

// async global->LDS, 16B per lane; dest = wave-uniform base + lane*16
__device__ __forceinline__ void glds16(const void* g, void* l) {
    __builtin_amdgcn_global_load_lds(
        (const __attribute__((address_space(1))) unsigned int*)g,
        (__attribute__((address_space(3))) unsigned int*)l, 16, 0, 0);
}

// 4x4 lane-group transpose step across lanes {q, q+16, q+32, q+48}:
// pure VALU: permlane32_swap + permlane16_swap. (Harness-verified in attn.)
__device__ __forceinline__ void xpose4(unsigned int& a, unsigned int& b) {
    uint2v r = __builtin_amdgcn_permlane32_swap(a, b, false, false);
    uint2v u = __builtin_amdgcn_permlane16_swap(r[0], r[1], false, false);
    a = u[0]; b = u[1];
}

// packed f32 pair -> 2 bf16 in one u32 (single v_cvt_pk_bf16_f32)
__device__ __forceinline__ unsigned int cvtpk(float a, float b) {
    unsigned int r;
    asm("v_cvt_pk_bf16_f32 %0, %1, %2" : "=v"(r) : "v"(a), "v"(b));
    return r;
}

// exp2 pair -> packed bf16 (attn softmax path)
__device__ __forceinline__ unsigned int exp2_pk(float a, float b) {
    float ea = __builtin_amdgcn_exp2f(a);
    float eb = __builtin_amdgcn_exp2f(b);
    return cvtpk(ea, eb);
}

// Two D-layout tiles (feature=quad*4+r in regs, token=lane&15) -> one MFMA
// operand chunk (token=lane&15, feature k=quad*8+j). (Verified in attn/R5.)
__device__ __forceinline__ bf16x8 pack_pair(f32x4 dA, f32x4 dB) {
    unsigned int RA0 = cvtpk(dA[0], dA[1]);
    unsigned int RA1 = cvtpk(dA[2], dA[3]);
    unsigned int RB0 = cvtpk(dB[0], dB[1]);
    unsigned int RB1 = cvtpk(dB[2], dB[3]);
    xpose4(RA0, RB0);
    xpose4(RA1, RB1);
    uint4v u = {RA0, RA1, RB0, RB1};
    return __builtin_bit_cast(bf16x8, u);
}

// ---- register-operand variant (act chunks in VGPRs) ----
template<int NK>
__device__ __forceinline__ void mm4(
    const __bf16* __restrict__ W, const int K, const int ft0,
    const bf16x8* act, const int qrow, const int quad, f32x4 acc[4])
{
#pragma unroll
    for (int i = 0; i < 4; i++) acc[i] = {0.f, 0.f, 0.f, 0.f};
#pragma unroll
    for (int kc = 0; kc < NK; kc++) {
        bf16x8 wf[4];
#pragma unroll
        for (int i = 0; i < 4; i++)
            wf[i] = *(const bf16x8*)&W[(size_t)((ft0 + i) * 16 + qrow) * K + kc * 32 + quad * 8];
#pragma unroll
        for (int i = 0; i < 4; i++)
            acc[i] = __builtin_amdgcn_mfma_f32_16x16x32_bf16(wf[i], act[kc], acc[i], 0, 0, 0);
    }
}

template<int NK, bool SILU>
__device__ __forceinline__ void stage_pack4(
    const __bf16* __restrict__ W, const int K, const int ft0,
    const float* __restrict__ bias,
    const bf16x8* act, const int qrow, const int quad, bf16x8* outc)
{
    f32x4 acc[4];
    mm4<NK>(W, K, ft0, act, qrow, quad, acc);
#pragma unroll
    for (int i = 0; i < 4; i++) {
        float4 bz = *(const float4*)&bias[(ft0 + i) * 16 + quad * 4];
        acc[i][0] += bz.x; acc[i][1] += bz.y; acc[i][2] += bz.z; acc[i][3] += bz.w;
        if (SILU) {
#pragma unroll
            for (int r = 0; r < 4; r++) {
                float v = acc[i][r];
                acc[i][r] = v / (1.f + __builtin_amdgcn_exp2f(-v * 1.4426950408889634f));
            }
        }
    }
    outc[0] = pack_pair(acc[0], acc[1]);
    outc[1] = pack_pair(acc[2], acc[3]);
}

// ---- LDS-operand variants (act chunk ds_read per K-step: low VGPR) ----
template<int NK>
__device__ __forceinline__ void mm4l(
    const __bf16* __restrict__ W, const int K, const int ft0,
    const __bf16* actb, const int lane, const int qrow, const int quad, f32x4 acc[4])
{
#pragma unroll
    for (int i = 0; i < 4; i++) acc[i] = {0.f, 0.f, 0.f, 0.f};
#pragma unroll
    for (int kc = 0; kc < NK; kc++) {
        bf16x8 a = *(const bf16x8*)&actb[((size_t)kc * 64 + lane) * 8];
        bf16x8 wf[4];
#pragma unroll
        for (int i = 0; i < 4; i++)
            wf[i] = *(const bf16x8*)&W[(size_t)((ft0 + i) * 16 + qrow) * K + kc * 32 + quad * 8];
#pragma unroll
        for (int i = 0; i < 4; i++)
            acc[i] = __builtin_amdgcn_mfma_f32_16x16x32_bf16(wf[i], a, acc[i], 0, 0, 0);
    }
}

template<int NK, bool SILU>
__device__ __forceinline__ void stage_pack4l(
    const __bf16* __restrict__ W, const int K, const int ft0,
    const float* __restrict__ bias, const __bf16* actb,
    const int lane, const int qrow, const int quad, bf16x8* outc)
{
    f32x4 acc[4];
    mm4l<NK>(W, K, ft0, actb, lane, qrow, quad, acc);
#pragma unroll
    for (int i = 0; i < 4; i++) {
        float4 bz = *(const float4*)&bias[(ft0 + i) * 16 + quad * 4];
        acc[i][0] += bz.x; acc[i][1] += bz.y; acc[i][2] += bz.z; acc[i][3] += bz.w;
        if (SILU) {
#pragma unroll
            for (int r = 0; r < 4; r++) {
                float v = acc[i][r];
                acc[i][r] = v / (1.f + __builtin_amdgcn_exp2f(-v * 1.4426950408889634f));
            }
        }
    }
    outc[0] = pack_pair(acc[0], acc[1]);
    outc[1] = pack_pair(acc[2], acc[3]);
}

template<int NK>
__device__ __forceinline__ void stage_d4l(
    const __bf16* __restrict__ W, const int K, const int ft0,
    const float* __restrict__ bias, const __bf16* actb,
    const int lane, const int qrow, const int quad, f32x4* dout)
{
    f32x4 acc[4];
    mm4l<NK>(W, K, ft0, actb, lane, qrow, quad, acc);
#pragma unroll
    for (int i = 0; i < 4; i++) {
        float4 bz = *(const float4*)&bias[(ft0 + i) * 16 + quad * 4];
        dout[i][0] = acc[i][0] + bz.x;
        dout[i][1] = acc[i][1] + bz.y;
        dout[i][2] = acc[i][2] + bz.z;
        dout[i][3] = acc[i][3] + bz.w;
    }
}

// ---------------------------------------------------------------------------
// convert_all: fp32 -> bf16 for x and the 8 weight matrices, one launch.
// ---------------------------------------------------------------------------
struct CvtArgs {
    const float* src[9];
    __bf16* dst[9];
    int start[10];
};

__global__ __launch_bounds__(256) void convert_all(CvtArgs a)
{
    int e = 0;
    const int bid = blockIdx.x;
#pragma unroll
    for (int i = 0; i < 8; i++) if (bid >= a.start[i + 1]) e = i + 1;
    const int idx = (bid - a.start[e]) * 256 + threadIdx.x;
    const float* s = a.src[e];
    float4 v0 = *(const float4*)&s[(size_t)idx * 8];
    float4 v1 = *(const float4*)&s[(size_t)idx * 8 + 4];
    bf16x8 o;
    o[0] = (__bf16)v0.x; o[1] = (__bf16)v0.y; o[2] = (__bf16)v0.z; o[3] = (__bf16)v0.w;
    o[4] = (__bf16)v1.x; o[5] = (__bf16)v1.y; o[6] = (__bf16)v1.z; o[7] = (__bf16)v1.w;
    *(bf16x8*)&a.dst[e][(size_t)idx * 8] = o;
}

// ---------------------------------------------------------------------------
// gemm128: BM=BN=128, BK=64; 4 waves each 64x64 (4x4 MFMA accs). For QKV.
// XOR swizzle: LDS slot (row,g) holds global chunk (row, g^(row&7)).
// ---------------------------------------------------------------------------
__global__ __launch_bounds__(256) void gemm128(
    const __bf16* __restrict__ A, const __bf16* __restrict__ W,
    const float* __restrict__ bias, const float* __restrict__ bias2, int bsplit,
    __bf16* __restrict__ C, int K, int ldc)
{
    __shared__ __bf16 As[128 * 64];
    __shared__ __bf16 Ws[128 * 64];
    const int tid = threadIdx.x;
    const int lane = tid & 63;
    const int wv = tid >> 6;
    const int wm = (wv >> 1) * 64;
    const int wn = (wv & 1) * 64;
    const int qrow = lane & 15;
    const int quad = lane >> 4;
    const int n0 = blockIdx.x * 128;
    const int m0 = blockIdx.y * 128;

    f32x4 acc[4][4];
#pragma unroll
    for (int i = 0; i < 4; i++)
#pragma unroll
        for (int j = 0; j < 4; j++) acc[i][j] = {0.f, 0.f, 0.f, 0.f};

    for (int k0 = 0; k0 < K; k0 += 64) {
        __syncthreads();
#pragma unroll
        for (int i = 0; i < 4; i++) {
            const int c = (wv * 4 + i) * 64 + lane;
            const int row = c >> 3, g = c & 7;
            const int gs = (g ^ (row & 7)) * 8;
            glds16(&A[(size_t)(m0 + row) * K + k0 + gs], &As[(wv * 4 + i) * 512]);
            glds16(&W[(size_t)(n0 + row) * K + k0 + gs], &Ws[(wv * 4 + i) * 512]);
        }
        __syncthreads();
#pragma unroll
        for (int ksub = 0; ksub < 2; ksub++) {
            const int gl = ksub * 4 + quad;
            bf16x8 af[4], bf[4];
#pragma unroll
            for (int mi = 0; mi < 4; mi++) {
                const int row = wm + mi * 16 + qrow;
                af[mi] = *(const bf16x8*)&As[row * 64 + (gl ^ (row & 7)) * 8];
            }
#pragma unroll
            for (int ni = 0; ni < 4; ni++) {
                const int row = wn + ni * 16 + qrow;
                bf[ni] = *(const bf16x8*)&Ws[row * 64 + (gl ^ (row & 7)) * 8];
            }
#pragma unroll
            for (int mi = 0; mi < 4; mi++)
#pragma unroll
                for (int ni = 0; ni < 4; ni++)
                    acc[mi][ni] = __builtin_amdgcn_mfma_f32_16x16x32_bf16(
                        af[mi], bf[ni], acc[mi][ni], 0, 0, 0);
        }
    }

    float bz[4];
#pragma unroll
    for (int ni = 0; ni < 4; ni++) {
        const int n = n0 + wn + ni * 16 + qrow;
        bz[ni] = (n < bsplit) ? bias[n] : bias2[n - bsplit];
    }
#pragma unroll
    for (int mi = 0; mi < 4; mi++)
#pragma unroll
        for (int r = 0; r < 4; r++) {
            const int row = m0 + wm + mi * 16 + quad * 4 + r;
#pragma unroll
            for (int ni = 0; ni < 4; ni++) {
                float v = acc[mi][ni][r] + bz[ni];
                C[(size_t)row * ldc + n0 + wn + ni * 16 + qrow] = (__bf16)v;
            }
        }
}

// ---------------------------------------------------------------------------
// attn_fused: 512-thread blocks.
// Blocks 0..1023: global MHA split-K x4 partials. 8 waves x 2 q-tiles x 16 q
//   = 256 q/block, 8 key-chunks of 64 keys each. P never touches LDS
//   (permlane transpose). exp2+bf16-pack via v_exp_f32 + v_cvt_pk_bf16_f32.
// Blocks 1024..1535: local window-5 MHA -> acat cols 256-511.
// ---------------------------------------------------------------------------
__global__ __launch_bounds__(512) void attn_fused(
    const __bf16* __restrict__ qkv, __bf16* __restrict__ Op,
    float* __restrict__ Lp, __bf16* __restrict__ acat)
{
    __shared__ __bf16 Kl[2][64 * 32];
    __shared__ __bf16 Vt[2][32 * 72];

    const int t = threadIdx.x;
    const int lane = t & 63;
    const int wv = t >> 6;          // 0..7

    if (blockIdx.x < 1024) {
        const int bid = blockIdx.x;
        const int sp = bid & 3;          // split-K x4
        const int qc = (bid >> 2) & 7;   // 8 chunks of 256 q
        const int h  = (bid >> 5) & 7;
        const int b  = bid >> 8;
        const int bS = b * Ss;
        const int q0 = qc * 256;

        const int qrow = lane & 15;
        const int quad = lane >> 4;
        const float cQ = 1.4426950408889634f * 0.17677669529663687f; // log2e/sqrt(32)

        bf16x8 qf[2];
#pragma unroll
        for (int tl = 0; tl < 2; tl++) {
            bf16x8 qraw = *(const bf16x8*)(qkv +
                (size_t)(bS + q0 + wv * 32 + tl * 16 + qrow) * QSTR + h * 32 + quad * 8);
#pragma unroll
            for (int i = 0; i < 8; i++) qf[tl][i] = (__bf16)((float)qraw[i] * cQ);
        }
        bf16x8 ones;
#pragma unroll
        for (int i = 0; i < 8; i++) ones[i] = (__bf16)1.0f;

        f32x4 o0[2], o1[2], lac[2];
#pragma unroll
        for (int tl = 0; tl < 2; tl++) {
            o0[tl] = {0.f, 0.f, 0.f, 0.f};
            o1[tl] = {0.f, 0.f, 0.f, 0.f};
            lac[tl] = {0.f, 0.f, 0.f, 0.f};
        }
        const f32x4 z = {0.f, 0.f, 0.f, 0.f};

        const int kc_c = wv * 64 + lane;
        const int kkey = kc_c >> 2, kdg = kc_c & 3;
        const int vkey = t & 63, vq = t >> 6;   // V: key, dim group of 4
        const int kc0 = sp * 8;                 // 8 chunks per split

        // prologue: prefetch chunk 0 (V into regs, K via glds into Kl[0])
        bf16x4 vreg = *(const bf16x4*)(qkv +
            (size_t)(bS + kc0 * 64 + vkey) * QSTR + 512 + h * 32 + vq * 4);
        if (wv < 4)
            glds16(qkv + (size_t)(bS + kc0 * 64 + kkey) * QSTR + 256 + h * 32 + kdg * 8,
                   &Kl[0][wv * 512]);

        for (int i = 0; i < 8; i++) {
            const int cur = i & 1;
#pragma unroll
            for (int e = 0; e < 4; e++) Vt[cur][(vq * 4 + e) * 72 + vkey] = vreg[e];
            __syncthreads();
            const int nx = (i < 7) ? (kc0 + i + 1) : (kc0 + 7);
            vreg = *(const bf16x4*)(qkv +
                (size_t)(bS + nx * 64 + vkey) * QSTR + 512 + h * 32 + vq * 4);
            if (i < 7 && wv < 4)
                glds16(qkv + (size_t)(bS + nx * 64 + kkey) * QSTR + 256 + h * 32 + kdg * 8,
                       &Kl[1 - cur][wv * 512]);

            // shared K/V fragments, read once, used by both q-tiles
            bf16x8 kf[4];
#pragma unroll
            for (int kg = 0; kg < 4; kg++)
                kf[kg] = *(const bf16x8*)&Kl[cur][(kg * 16 + qrow) * 32 + quad * 8];
            bf16x8 vf00 = *(const bf16x8*)&Vt[cur][qrow * 72 + quad * 8];
            bf16x8 vf01 = *(const bf16x8*)&Vt[cur][qrow * 72 + 32 + quad * 8];
            bf16x8 vf10 = *(const bf16x8*)&Vt[cur][(16 + qrow) * 72 + quad * 8];
            bf16x8 vf11 = *(const bf16x8*)&Vt[cur][(16 + qrow) * 72 + 32 + quad * 8];

#pragma unroll
            for (int tl = 0; tl < 2; tl++) {
                f32x4 s[4];
#pragma unroll
                for (int kg = 0; kg < 4; kg++)
                    s[kg] = __builtin_amdgcn_mfma_f32_16x16x32_bf16(
                        kf[kg], qf[tl], z, 0, 0, 0);
                unsigned int R[4][2];
#pragma unroll
                for (int kg = 0; kg < 4; kg++) {
                    R[kg][0] = exp2_pk(s[kg][0], s[kg][1]);
                    R[kg][1] = exp2_pk(s[kg][2], s[kg][3]);
                }
                xpose4(R[0][0], R[1][0]);
                xpose4(R[0][1], R[1][1]);
                xpose4(R[2][0], R[3][0]);
                xpose4(R[2][1], R[3][1]);
                uint4v p0u = {R[0][0], R[0][1], R[1][0], R[1][1]};
                uint4v p1u = {R[2][0], R[2][1], R[3][0], R[3][1]};
                bf16x8 pf0 = __builtin_bit_cast(bf16x8, p0u);
                bf16x8 pf1 = __builtin_bit_cast(bf16x8, p1u);

                o0[tl] = __builtin_amdgcn_mfma_f32_16x16x32_bf16(vf00, pf0, o0[tl], 0, 0, 0);
                o1[tl] = __builtin_amdgcn_mfma_f32_16x16x32_bf16(vf10, pf0, o1[tl], 0, 0, 0);
                lac[tl] = __builtin_amdgcn_mfma_f32_16x16x32_bf16(ones, pf0, lac[tl], 0, 0, 0);
                o0[tl] = __builtin_amdgcn_mfma_f32_16x16x32_bf16(vf01, pf1, o0[tl], 0, 0, 0);
                o1[tl] = __builtin_amdgcn_mfma_f32_16x16x32_bf16(vf11, pf1, o1[tl], 0, 0, 0);
                lac[tl] = __builtin_amdgcn_mfma_f32_16x16x32_bf16(ones, pf1, lac[tl], 0, 0, 0);
            }
        }

#pragma unroll
        for (int tl = 0; tl < 2; tl++) {
            const int gid = (b * 8 + h) * 2048 + q0 + wv * 32 + tl * 16 + qrow;
            __bf16* po = Op + (size_t)sp * 2097152 + (size_t)gid * 32;
            bf16x4 w0, w1;
#pragma unroll
            for (int r = 0; r < 4; r++) {
                w0[r] = (__bf16)o0[tl][r];
                w1[r] = (__bf16)o1[tl][r];
            }
            *(bf16x4*)&po[quad * 4]      = w0;
            *(bf16x4*)&po[16 + quad * 4] = w1;
            if (quad == 0) Lp[sp * 65536 + gid] = lac[tl][0];
        }
    } else {
        // local window-5 attention: 8 lanes per (b,s,h) row, 8 rows per wave
        const int w = (blockIdx.x - 1024) * 8 + wv;  // 0..4095
        const int g = lane >> 3;                      // row-in-wave 0..7
        const int l8 = lane & 7;                      // dim-group (8 bf16)
        const int R = w * 8 + g;                      // 0..32767
        const int h = R & 3;
        const int s = (R >> 2) & 2047;
        const int b = R >> 13;

        float qv[8];
        {
            bf16x8 q8 = *(const bf16x8*)&qkv[(size_t)(b * Ss + s) * QSTR + 768 + h * 64 + l8 * 8];
#pragma unroll
            for (int e = 0; e < 8; e++) qv[e] = (float)q8[e];
        }

        float sc[5];
        bf16x8 v8[5];
#pragma unroll
        for (int j = 0; j < 5; j++) {
            int pos = s + j - 2;
            bool valid = (pos >= 0) && (pos < Ss);
            int cpos = valid ? pos : 0;
            const size_t rb = (size_t)(b * Ss + cpos) * QSTR;
            bf16x8 k8 = *(const bf16x8*)&qkv[rb + 1024 + h * 64 + l8 * 8];
            v8[j]     = *(const bf16x8*)&qkv[rb + 1280 + h * 64 + l8 * 8];
            float p = 0.f;
#pragma unroll
            for (int e = 0; e < 8; e++) p += qv[e] * (float)k8[e];
            p += __shfl_xor(p, 1, 64);
            p += __shfl_xor(p, 2, 64);
            p += __shfl_xor(p, 4, 64);
            sc[j] = valid ? p * 0.125f : -1e30f;
        }
        float m = sc[0];
#pragma unroll
        for (int j = 1; j < 5; j++) m = fmaxf(m, sc[j]);
        float l = 0.f;
        float o[8];
#pragma unroll
        for (int e = 0; e < 8; e++) o[e] = 0.f;
#pragma unroll
        for (int j = 0; j < 5; j++) {
            float pe = __builtin_amdgcn_exp2f((sc[j] - m) * 1.4426950408889634f);
            l += pe;
#pragma unroll
            for (int e = 0; e < 8; e++) o[e] += pe * (float)v8[j][e];
        }
        const float li = 1.f / l;
        bf16x8 r;
#pragma unroll
        for (int e = 0; e < 8; e++) r[e] = (__bf16)(o[e] * li);
        *(bf16x8*)&acat[(size_t)(b * Ss + s) * 512 + 256 + h * 64 + l8 * 8] = r;
    }
}

// ---------------------------------------------------------------------------
// epilogue: ONE kernel for combine + out-proj + fusion-MLP + LN1 + FFN + LN2.
// 512 blocks x 256 threads (4 waves). Each BLOCK owns 16 tokens; the 4 waves
// split every stage's OUTPUT features 4-ways (disjoint weight rows), then
// exchange quarter-results through a double-buffered 16-slot LDS buffer.
// KEY FIX vs R6: GEMM stages read their activation operand chunk from LDS
// per K-step (mm4l) instead of holding act[16] in VGPRs -> live state ~80
// regs, no scratch spill (R6: 160-VGPR cap forced ~54 MB spill traffic).
// __launch_bounds__(256,2) caps VGPR at 256 (grid-limited to 2 blocks/CU
// anyway). Same per-stage math as R5/R6 (numerically verified).
// ---------------------------------------------------------------------------
__global__ __launch_bounds__(256, 2) void epilogue(
    const __bf16* __restrict__ Op, const float* __restrict__ Lp,
    const __bf16* __restrict__ acat, const float* __restrict__ x,
    const __bf16* __restrict__ w_gout, const float* __restrict__ g_out_b,
    const __bf16* __restrict__ w_tout, const float* __restrict__ t_out_b,
    const __bf16* __restrict__ w_f1, const float* __restrict__ fus_b1,
    const __bf16* __restrict__ w_f2, const float* __restrict__ fus_b2,
    const __bf16* __restrict__ w_n1, const float* __restrict__ ffn_b1,
    const __bf16* __restrict__ w_n2, const float* __restrict__ ffn_b2,
    const float* __restrict__ gn_g, const float* __restrict__ gn_b,
    const float* __restrict__ fn_g, const float* __restrict__ fn_b,
    float* __restrict__ out)
{
    __shared__ __bf16 ex[2][16 * 64 * 8];   // [buf][(slot*64+lane)*8] 16B units
    const int tid = threadIdx.x;
    const int lane = tid & 63;
    const int wv = tid >> 6;                // 0..3
    const int qrow = lane & 15;
    const int quad = lane >> 4;
    const int t = blockIdx.x * 16 + qrow;   // token 0..8191
    const int b = t >> 11;
    const int q = t & 2047;

#define SLOT(buf, slot) ((bf16x8*)&ex[buf][((slot) * 64 + lane) * 8])

    // ---- S0: assemble acat operand chunks (split across waves) ----
#pragma unroll
    for (int e = 0; e < 2; e++) {
        const int h = wv * 2 + e;
        const size_t gid = (size_t)(b * 8 + h) * 2048 + q;
        const float li = 1.f / (Lp[gid] + Lp[65536 + gid] +
                                Lp[131072 + gid] + Lp[196608 + gid]);
        const __bf16* base = Op + gid * 32 + quad * 8;
        bf16x8 a0 = *(const bf16x8*)&base[0];
        bf16x8 a1 = *(const bf16x8*)&base[2097152];
        bf16x8 a2 = *(const bf16x8*)&base[4194304];
        bf16x8 a3 = *(const bf16x8*)&base[6291456];
        unsigned int w[4];
#pragma unroll
        for (int p = 0; p < 4; p++) {
            float v0 = ((float)a0[2*p]   + (float)a1[2*p]   +
                        (float)a2[2*p]   + (float)a3[2*p])   * li;
            float v1 = ((float)a0[2*p+1] + (float)a1[2*p+1] +
                        (float)a2[2*p+1] + (float)a3[2*p+1]) * li;
            w[p] = cvtpk(v0, v1);
        }
        uint4v u = {w[0], w[1], w[2], w[3]};
        *SLOT(0, h) = __builtin_bit_cast(bf16x8, u);
        *SLOT(0, 8 + h) = *(const bf16x8*)&acat[(size_t)t * 512 + 256 + h * 32 + quad * 8];
    }
    __syncthreads();

    const __bf16* eb0  = &ex[0][0];
    const __bf16* eb0h = &ex[0][8 * 64 * 8];
    const __bf16* eb1  = &ex[1][0];

    // ---- S1: fcomb = [buf0[0:8]*w_gout^T+gb | buf0[8:16]*w_tout^T+tb] ----
    bf16x8 oc[4];
    if (wv < 2) {
        stage_pack4l<8, false>(w_gout, 256, wv * 8,     g_out_b, eb0, lane, qrow, quad, &oc[0]);
        stage_pack4l<8, false>(w_gout, 256, wv * 8 + 4, g_out_b, eb0, lane, qrow, quad, &oc[2]);
    } else {
        stage_pack4l<8, false>(w_tout, 256, (wv - 2) * 8,     t_out_b, eb0h, lane, qrow, quad, &oc[0]);
        stage_pack4l<8, false>(w_tout, 256, (wv - 2) * 8 + 4, t_out_b, eb0h, lane, qrow, quad, &oc[2]);
    }
#pragma unroll
    for (int i = 0; i < 4; i++) *SLOT(1, wv * 4 + i) = oc[i];
    __syncthreads();

    // ---- S2: h1 = silu(buf1 * w_f1^T + fus_b1), K=512 N=512 ----
    stage_pack4l<16, true>(w_f1, 512, wv * 8,     fus_b1, eb1, lane, qrow, quad, &oc[0]);
    stage_pack4l<16, true>(w_f1, 512, wv * 8 + 4, fus_b1, eb1, lane, qrow, quad, &oc[2]);
    __syncthreads();   // all reads of buf1 done before overwrite below? No:
    // oc writes go to buf0; buf1 is read-only this stage. The barrier above
    // is to ensure every wave finished reading buf1... actually not needed
    // for buf0 writes; keep it minimal: write then barrier.
#pragma unroll
    for (int i = 0; i < 4; i++) *SLOT(0, wv * 4 + i) = oc[i];
    __syncthreads();

    // ---- S3: xfb = buf0(h1) * w_f2^T + fus_b2 (own quarter, fp32) + x ----
    f32x4 dp[4];
    stage_d4l<16>(w_f2, 512, wv * 4, fus_b2, eb0, lane, qrow, quad, dp);
#pragma unroll
    for (int i = 0; i < 4; i++) {
        float4 xr = *(const float4*)&x[(size_t)t * 256 + (wv * 4 + i) * 16 + quad * 4];
        dp[i][0] += xr.x; dp[i][1] += xr.y; dp[i][2] += xr.z; dp[i][3] += xr.w;
    }
    __syncthreads();   // everyone done reading buf0/buf1 before d-exchange in buf1
#pragma unroll
    for (int i = 0; i < 4; i++) *(f32x4*)SLOT(1, wv * 4 + i) = dp[i];
    __syncthreads();
    f32x4 d[16];
#pragma unroll
    for (int ft = 0; ft < 16; ft++) d[ft] = *(f32x4*)SLOT(1, ft);

    // ---- LN1 (redundant per wave) ----
    float s = 0.f;
#pragma unroll
    for (int ft = 0; ft < 16; ft++) s += d[ft][0] + d[ft][1] + d[ft][2] + d[ft][3];
    s += __shfl_xor(s, 16, 64);
    s += __shfl_xor(s, 32, 64);
    const float mu = s * (1.f / 256.f);
    float sq = 0.f;
#pragma unroll
    for (int ft = 0; ft < 16; ft++)
#pragma unroll
        for (int r = 0; r < 4; r++) { d[ft][r] -= mu; sq += d[ft][r] * d[ft][r]; }
    sq += __shfl_xor(sq, 16, 64);
    sq += __shfl_xor(sq, 32, 64);
    const float rs = rsqrtf(sq * (1.f / 256.f) + 1e-5f);
#pragma unroll
    for (int ft = 0; ft < 16; ft++) {
        float4 gg = *(const float4*)&gn_g[ft * 16 + quad * 4];
        float4 bb = *(const float4*)&gn_b[ft * 16 + quad * 4];
        d[ft][0] = d[ft][0] * rs * gg.x + bb.x;
        d[ft][1] = d[ft][1] * rs * gg.y + bb.y;
        d[ft][2] = d[ft][2] * rs * gg.z + bb.z;
        d[ft][3] = d[ft][3] * rs * gg.w + bb.w;
    }
    bf16x8 actx2[8];
#pragma unroll
    for (int c = 0; c < 8; c++)
        actx2[c] = pack_pair(d[2 * c], d[2 * c + 1]);
    // own quarter of x2 (fp32) for the S5 residual; full d[] dies here
    f32x4 x2own[4];
#pragma unroll
    for (int i = 0; i < 4; i++) x2own[i] = d[wv * 4 + i];

    // ---- S4: h2 = silu(x2 * w_n1^T + ffn_b1), K=256 N=512 (reg operand) ----
    stage_pack4<8, true>(w_n1, 256, wv * 8,     ffn_b1, actx2, qrow, quad, &oc[0]);
    stage_pack4<8, true>(w_n1, 256, wv * 8 + 4, ffn_b1, actx2, qrow, quad, &oc[2]);
#pragma unroll
    for (int i = 0; i < 4; i++) *SLOT(0, wv * 4 + i) = oc[i];
    __syncthreads();

    // ---- S5: xffb = buf0(h2) * w_n2^T + ffn_b2 (own quarter) + x2 ----
    stage_d4l<16>(w_n2, 512, wv * 4, ffn_b2, eb0, lane, qrow, quad, dp);
#pragma unroll
    for (int i = 0; i < 4; i++)
#pragma unroll
        for (int r = 0; r < 4; r++) dp[i][r] += x2own[i][r];
    __syncthreads();
#pragma unroll
    for (int i = 0; i < 4; i++) *(f32x4*)SLOT(1, wv * 4 + i) = dp[i];
    __syncthreads();
#pragma unroll
    for (int ft = 0; ft < 16; ft++) d[ft] = *(f32x4*)SLOT(1, ft);

    // ---- LN2 (sums redundant; each wave writes its own quarter) ----
    float s2 = 0.f;
#pragma unroll
    for (int ft = 0; ft < 16; ft++) s2 += d[ft][0] + d[ft][1] + d[ft][2] + d[ft][3];
    s2 += __shfl_xor(s2, 16, 64);
    s2 += __shfl_xor(s2, 32, 64);
    const float mu2 = s2 * (1.f / 256.f);
    float sq2 = 0.f;
#pragma unroll
    for (int ft = 0; ft < 16; ft++)
#pragma unroll
        for (int r = 0; r < 4; r++) { d[ft][r] -= mu2; sq2 += d[ft][r] * d[ft][r]; }
    sq2 += __shfl_xor(sq2, 16, 64);
    sq2 += __shfl_xor(sq2, 32, 64);
    const float rs2 = rsqrtf(sq2 * (1.f / 256.f) + 1e-5f);
#pragma unroll
    for (int i = 0; i < 4; i++) {
        const int ft = wv * 4 + i;
        float4 gg = *(const float4*)&fn_g[ft * 16 + quad * 4];
        float4 bb = *(const float4*)&fn_b[ft * 16 + quad * 4];
        f32x4 o;
        o[0] = d[ft][0] * rs2 * gg.x + bb.x;
        o[1] = d[ft][1] * rs2 * gg.y + bb.y;
        o[2] = d[ft][2] * rs2 * gg.z + bb.z;
        o[3] = d[ft][3] * rs2 * gg.w + bb.w;
        *(f32x4*)&out[(size_t)t * 256 + ft * 16 + quad * 4] = o;
    }
#undef SLOT
}

// ---------------------------------------------------------------------------
extern "C" void kernel_launch(void* const* d_in, const int* in_sizes, int n_in,
                              void* d_out, int out_size, void* d_ws, size_t ws_size,
                              hipStream_t stream)
{
    const float* x      = (const float*)d_in[0];
    const float* g_in_w = (const float*)d_in[1];
    const float* g_in_b = (const float*)d_in[2];
    const float* g_out_w= (const float*)d_in[3];
    const float* g_out_b= (const float*)d_in[4];
    const float* t_in_w = (const float*)d_in[5];
    const float* t_in_b = (const float*)d_in[6];
    const float* t_out_w= (const float*)d_in[7];
    const float* t_out_b= (const float*)d_in[8];
    const float* fus_w1 = (const float*)d_in[9];
    const float* fus_b1 = (const float*)d_in[10];
    const float* fus_w2 = (const float*)d_in[11];
    const float* fus_b2 = (const float*)d_in[12];
    const float* ffn_w1 = (const float*)d_in[13];
    const float* ffn_b1 = (const float*)d_in[14];
    const float* ffn_w2 = (const float*)d_in[15];
    const float* ffn_b2 = (const float*)d_in[16];
    const float* gn_g   = (const float*)d_in[17];
    const float* gn_b   = (const float*)d_in[18];
    const float* fn_g   = (const float*)d_in[19];
    const float* fn_b   = (const float*)d_in[20];
    float* out = (float*)d_out;
    float* ws  = (float*)d_ws;

    // ws layout in f32 slots
    __bf16* xb     = (__bf16*)(ws);                 // [0, 1048576)
    __bf16* wb     = (__bf16*)(ws + 1048576);       // [1048576, 1638400)
    __bf16* qkvgl  = (__bf16*)(ws + 1638400);       // [1638400, 7929856)  8192x1536
    __bf16* acat   = (__bf16*)(ws + 7929856);       // [7929856, 10027008) 8192x512
    // attention partials: live only between attn_fused and epilogue.
    __bf16* Op = (__bf16*)(ws + 10027008);          // 4x65536x32 bf16
    float*  Lp = ws + 18415616;                     // 4x65536 fp32

    __bf16* w_gin  = wb;              // [1536x256] combined (g rows 0-767, t 768-1535)
    __bf16* w_gout = wb + 393216;
    __bf16* w_tout = wb + 458752;
    __bf16* w_f1   = wb + 524288;
    __bf16* w_f2   = wb + 786432;
    __bf16* w_n1   = wb + 917504;
    __bf16* w_n2   = wb + 1048576;

    CvtArgs ca;
    ca.src[0] = x;      ca.dst[0] = xb;
    ca.src[1] = g_in_w; ca.dst[1] = w_gin;
    ca.src[2] = t_in_w; ca.dst[2] = w_gin + 196608;
    ca.src[3] = g_out_w;ca.dst[3] = w_gout;
    ca.src[4] = t_out_w;ca.dst[4] = w_tout;
    ca.src[5] = fus_w1; ca.dst[5] = w_f1;
    ca.src[6] = fus_w2; ca.dst[6] = w_f2;
    ca.src[7] = ffn_w1; ca.dst[7] = w_n1;
    ca.src[8] = ffn_w2; ca.dst[8] = w_n2;
    int st[10] = {0, 1024, 1120, 1216, 1248, 1280, 1408, 1472, 1536, 1600};
    for (int i = 0; i < 10; i++) ca.start[i] = st[i];

    convert_all<<<dim3(1600), 256, 0, stream>>>(ca);

    // Combined QKV projection: M=8192, N=1536, K=256 -> qkvgl (128x128 tiles)
    gemm128<<<dim3(12, 64), 256, 0, stream>>>(
        xb, w_gin, g_in_b, t_in_b, 768, qkvgl, 256, QSTR);
    // Global attention partials split-K x4 (blocks 0-1023) + local (1024-1535)
    attn_fused<<<dim3(1536), 512, 0, stream>>>(qkvgl, Op, Lp, acat);
    // Everything else: one fused token-parallel kernel (4-way feature split)
    epilogue<<<dim3(512), 256, 0, stream>>>(
        Op, Lp, acat, x,
        w_gout, g_out_b, w_tout, t_out_b,
        w_f1, fus_b1, w_f2, fus_b2,
        w_n1, ffn_b1, w_n2, ffn_b2,
        gn_g, gn_b, fn_g, fn_b, out);
}

// Round 8
// 207.172 us; speedup vs baseline: 1.2644x; 1.2399x over previous
//
#include <hip/hip_runtime.h>

constexpr int Bb = 4;
constexpr int Ss = 2048;
constexpr int QSTR = 1536;   // combined qkv row stride (g 0..767, t 768..1535)

typedef __bf16 bf16x8 __attribute__((ext_vector_type(8)));
typedef __bf16 bf16x4 __attribute__((ext_vector_type(4)));
typedef float  f32x4  __attribute__((ext_vector_type(4)));
typedef unsigned int uint2v __attribute__((ext_vector_type(2)));
typedef unsigned int uint4v __attribute__((ext_vector_type(4)));

// async global->LDS, 16B per lane; dest = wave-uniform base + lane*16
__device__ __forceinline__ void glds16(const void* g, void* l) {
    __builtin_amdgcn_global_load_lds(
        (const __attribute__((address_space(1))) unsigned int*)g,
        (__attribute__((address_space(3))) unsigned int*)l, 16, 0, 0);
}

// 4x4 lane-group transpose step across lanes {q, q+16, q+32, q+48}:
// pure VALU: permlane32_swap + permlane16_swap. (Harness-verified in attn.)
__device__ __forceinline__ void xpose4(unsigned int& a, unsigned int& b) {
    uint2v r = __builtin_amdgcn_permlane32_swap(a, b, false, false);
    uint2v u = __builtin_amdgcn_permlane16_swap(r[0], r[1], false, false);
    a = u[0]; b = u[1];
}

// exp2 pair -> packed bf16 in one u32 (bare v_exp_f32 + v_cvt_pk_bf16_f32)
__device__ __forceinline__ unsigned int exp2_pk(float a, float b) {
    float ea = __builtin_amdgcn_exp2f(a);
    float eb = __builtin_amdgcn_exp2f(b);
    unsigned int r;
    asm("v_cvt_pk_bf16_f32 %0, %1, %2" : "=v"(r) : "v"(ea), "v"(eb));
    return r;
}

// ---------------------------------------------------------------------------
// convert_all: fp32 -> bf16 for x and the 8 weight matrices, one launch.
// ---------------------------------------------------------------------------
struct CvtArgs {
    const float* src[9];
    __bf16* dst[9];
    int start[10];
};

__global__ __launch_bounds__(256) void convert_all(CvtArgs a)
{
    int e = 0;
    const int bid = blockIdx.x;
#pragma unroll
    for (int i = 0; i < 8; i++) if (bid >= a.start[i + 1]) e = i + 1;
    const int idx = (bid - a.start[e]) * 256 + threadIdx.x;
    const float* s = a.src[e];
    float4 v0 = *(const float4*)&s[(size_t)idx * 8];
    float4 v1 = *(const float4*)&s[(size_t)idx * 8 + 4];
    bf16x8 o;
    o[0] = (__bf16)v0.x; o[1] = (__bf16)v0.y; o[2] = (__bf16)v0.z; o[3] = (__bf16)v0.w;
    o[4] = (__bf16)v1.x; o[5] = (__bf16)v1.y; o[6] = (__bf16)v1.z; o[7] = (__bf16)v1.w;
    *(bf16x8*)&a.dst[e][(size_t)idx * 8] = o;
}

// ---------------------------------------------------------------------------
// gemm128: BM=BN=128, BK=64; 4 waves each 64x64 (4x4 MFMA accs). For QKV.
// XOR swizzle: LDS slot (row,g) holds global chunk (row, g^(row&7)).
// ---------------------------------------------------------------------------
__global__ __launch_bounds__(256) void gemm128(
    const __bf16* __restrict__ A, const __bf16* __restrict__ W,
    const float* __restrict__ bias, const float* __restrict__ bias2, int bsplit,
    __bf16* __restrict__ C, int K, int ldc)
{
    __shared__ __bf16 As[128 * 64];
    __shared__ __bf16 Ws[128 * 64];
    const int tid = threadIdx.x;
    const int lane = tid & 63;
    const int wv = tid >> 6;
    const int wm = (wv >> 1) * 64;
    const int wn = (wv & 1) * 64;
    const int qrow = lane & 15;
    const int quad = lane >> 4;
    const int n0 = blockIdx.x * 128;
    const int m0 = blockIdx.y * 128;

    f32x4 acc[4][4];
#pragma unroll
    for (int i = 0; i < 4; i++)
#pragma unroll
        for (int j = 0; j < 4; j++) acc[i][j] = {0.f, 0.f, 0.f, 0.f};

    for (int k0 = 0; k0 < K; k0 += 64) {
        __syncthreads();
#pragma unroll
        for (int i = 0; i < 4; i++) {
            const int c = (wv * 4 + i) * 64 + lane;
            const int row = c >> 3, g = c & 7;
            const int gs = (g ^ (row & 7)) * 8;
            glds16(&A[(size_t)(m0 + row) * K + k0 + gs], &As[(wv * 4 + i) * 512]);
            glds16(&W[(size_t)(n0 + row) * K + k0 + gs], &Ws[(wv * 4 + i) * 512]);
        }
        __syncthreads();
#pragma unroll
        for (int ksub = 0; ksub < 2; ksub++) {
            const int gl = ksub * 4 + quad;
            bf16x8 af[4], bf[4];
#pragma unroll
            for (int mi = 0; mi < 4; mi++) {
                const int row = wm + mi * 16 + qrow;
                af[mi] = *(const bf16x8*)&As[row * 64 + (gl ^ (row & 7)) * 8];
            }
#pragma unroll
            for (int ni = 0; ni < 4; ni++) {
                const int row = wn + ni * 16 + qrow;
                bf[ni] = *(const bf16x8*)&Ws[row * 64 + (gl ^ (row & 7)) * 8];
            }
#pragma unroll
            for (int mi = 0; mi < 4; mi++)
#pragma unroll
                for (int ni = 0; ni < 4; ni++)
                    acc[mi][ni] = __builtin_amdgcn_mfma_f32_16x16x32_bf16(
                        af[mi], bf[ni], acc[mi][ni], 0, 0, 0);
        }
    }

    float bz[4];
#pragma unroll
    for (int ni = 0; ni < 4; ni++) {
        const int n = n0 + wn + ni * 16 + qrow;
        bz[ni] = (n < bsplit) ? bias[n] : bias2[n - bsplit];
    }
#pragma unroll
    for (int mi = 0; mi < 4; mi++)
#pragma unroll
        for (int r = 0; r < 4; r++) {
            const int row = m0 + wm + mi * 16 + quad * 4 + r;
#pragma unroll
            for (int ni = 0; ni < 4; ni++) {
                float v = acc[mi][ni][r] + bz[ni];
                C[(size_t)row * ldc + n0 + wn + ni * 16 + qrow] = (__bf16)v;
            }
        }
}

// ---------------------------------------------------------------------------
// gemm_mid: BM=64, BN=64, BK=128; 4 waves as 2(m)x2(n), each 32x32 (2x2 accs).
// Second-weight select: blocks with blockIdx.x >= nsplit use W1/bias1,
// A0+aoff1, coff1. (Verified R4.)
// ---------------------------------------------------------------------------
template<bool SILU, bool OUT_BF16>
__global__ __launch_bounds__(256) void gemm_mid(
    const __bf16* __restrict__ A0, const __bf16* __restrict__ W0,
    const float* __restrict__ bias0, const __bf16* __restrict__ W1,
    const float* __restrict__ bias1, int nsplit, int aoff1, int coff1,
    void* __restrict__ C, int lda, int K, int ldc)
{
    __shared__ __bf16 As[64 * 128];
    __shared__ __bf16 Ws[64 * 128];
    const int tid = threadIdx.x;
    const int lane = tid & 63;
    const int wv = tid >> 6;
    const int wm = (wv >> 1) * 32;
    const int wn = (wv & 1) * 32;
    const int qrow = lane & 15;
    const int quad = lane >> 4;
    const bool second = (int)blockIdx.x >= nsplit;
    const int bx = second ? (blockIdx.x - nsplit) : blockIdx.x;
    const __bf16* A = second ? (A0 + aoff1) : A0;
    const __bf16* W = second ? W1 : W0;
    const float* bias = second ? bias1 : bias0;
    const int coff = second ? coff1 : 0;
    const int n0 = bx * 64;
    const int m0 = blockIdx.y * 64;

    f32x4 acc[2][2];
#pragma unroll
    for (int i = 0; i < 2; i++)
#pragma unroll
        for (int j = 0; j < 2; j++) acc[i][j] = {0.f, 0.f, 0.f, 0.f};

    for (int k0 = 0; k0 < K; k0 += 128) {
        __syncthreads();
#pragma unroll
        for (int i = 0; i < 4; i++) {
            const int c = (wv * 4 + i) * 64 + lane;
            const int row = c >> 4, s = c & 15;
            const int gs = ((s & 8) | ((s ^ row) & 7)) * 8;
            glds16(&A[(size_t)(m0 + row) * lda + k0 + gs], &As[(wv * 4 + i) * 512]);
            glds16(&W[(size_t)(n0 + row) * K + k0 + gs], &Ws[(wv * 4 + i) * 512]);
        }
        __syncthreads();
#pragma unroll
        for (int ksub = 0; ksub < 4; ksub++) {
            const int gl = ksub * 4 + quad;
            bf16x8 af[2], bf[2];
#pragma unroll
            for (int mi = 0; mi < 2; mi++) {
                const int row = wm + mi * 16 + qrow;
                const int s = (gl & 8) | ((gl ^ row) & 7);
                af[mi] = *(const bf16x8*)&As[row * 128 + s * 8];
            }
#pragma unroll
            for (int ni = 0; ni < 2; ni++) {
                const int row = wn + ni * 16 + qrow;
                const int s = (gl & 8) | ((gl ^ row) & 7);
                bf[ni] = *(const bf16x8*)&Ws[row * 128 + s * 8];
            }
#pragma unroll
            for (int mi = 0; mi < 2; mi++)
#pragma unroll
                for (int ni = 0; ni < 2; ni++)
                    acc[mi][ni] = __builtin_amdgcn_mfma_f32_16x16x32_bf16(
                        af[mi], bf[ni], acc[mi][ni], 0, 0, 0);
        }
    }

    float bz[2];
#pragma unroll
    for (int ni = 0; ni < 2; ni++) bz[ni] = bias[n0 + wn + ni * 16 + qrow];

#pragma unroll
    for (int mi = 0; mi < 2; mi++)
#pragma unroll
        for (int r = 0; r < 4; r++) {
            const int row = m0 + wm + mi * 16 + quad * 4 + r;
#pragma unroll
            for (int ni = 0; ni < 2; ni++) {
                float v = acc[mi][ni][r] + bz[ni];
                if (SILU) v = v / (1.f + __expf(-v));
                const int col = coff + n0 + wn + ni * 16 + qrow;
                if (OUT_BF16)
                    ((__bf16*)C)[(size_t)row * ldc + col] = (__bf16)v;
                else
                    ((float*)C)[(size_t)row * ldc + col] = v;
            }
        }
}

// ---------------------------------------------------------------------------
// gemm_ln: full-width GEMM (BM=16 tokens, BN=256 = ALL features, K=512)
// + residual + LayerNorm, fused. 512 blocks x 4 waves; wave wv owns feature
// range [wv*64, wv*64+64). Staging/fragment/MFMA algebra identical to
// gemm_mid (verified); after the K loop the block holds complete 256-wide
// rows, so LN runs in-block: per-lane partials -> qrow butterfly shuffle ->
// tiny LDS cross-wave reduce (2 barriers). Replaces gemm_mid+ln_residual
// pairs (saves 2 launches + xfb round trip).
// ---------------------------------------------------------------------------
template<bool OBF>
__global__ __launch_bounds__(256) void gemm_ln(
    const __bf16* __restrict__ A, const __bf16* __restrict__ W,
    const float* __restrict__ bias, const float* __restrict__ res,
    const float* __restrict__ g, const float* __restrict__ be,
    float* __restrict__ out, __bf16* __restrict__ outb)
{
    __shared__ __bf16 As[16 * 128];
    __shared__ __bf16 Ws[256 * 128];
    __shared__ float lnp[2][16][4];
    const int tid = threadIdx.x;
    const int lane = tid & 63;
    const int wv = tid >> 6;
    const int qrow = lane & 15;
    const int quad = lane >> 4;
    const int m0 = blockIdx.x * 16;

    f32x4 acc[4];
#pragma unroll
    for (int ni = 0; ni < 4; ni++) acc[ni] = {0.f, 0.f, 0.f, 0.f};

    for (int k0 = 0; k0 < 512; k0 += 128) {
        __syncthreads();
        {
            const int c = wv * 64 + lane;          // 256 chunks = 16 rows x 16
            const int row = c >> 4, s = c & 15;
            const int gs = ((s & 8) | ((s ^ row) & 7)) * 8;
            glds16(&A[(size_t)(m0 + row) * 512 + k0 + gs], &As[wv * 512]);
        }
#pragma unroll
        for (int i = 0; i < 16; i++) {             // 4096 chunks = 256 rows x 16
            const int c = (wv * 16 + i) * 64 + lane;
            const int row = c >> 4, s = c & 15;
            const int gs = ((s & 8) | ((s ^ row) & 7)) * 8;
            glds16(&W[(size_t)row * 512 + k0 + gs], &Ws[(wv * 16 + i) * 512]);
        }
        __syncthreads();
#pragma unroll
        for (int ksub = 0; ksub < 4; ksub++) {
            const int gl = ksub * 4 + quad;
            bf16x8 af, bf[4];
            {
                const int row = qrow;
                const int s = (gl & 8) | ((gl ^ row) & 7);
                af = *(const bf16x8*)&As[row * 128 + s * 8];
            }
#pragma unroll
            for (int ni = 0; ni < 4; ni++) {
                const int row = wv * 64 + ni * 16 + qrow;
                const int s = (gl & 8) | ((gl ^ row) & 7);
                bf[ni] = *(const bf16x8*)&Ws[row * 128 + s * 8];
            }
#pragma unroll
            for (int ni = 0; ni < 4; ni++)
                acc[ni] = __builtin_amdgcn_mfma_f32_16x16x32_bf16(
                    af, bf[ni], acc[ni], 0, 0, 0);
        }
    }

    // d[ni][r] = acc + bias + residual; token = quad*4+r, feature = wv*64+ni*16+qrow
    f32x4 d[4];
#pragma unroll
    for (int ni = 0; ni < 4; ni++) {
        const int f = wv * 64 + ni * 16 + qrow;
        const float bz = bias[f];
#pragma unroll
        for (int r = 0; r < 4; r++)
            d[ni][r] = acc[ni][r] + bz + res[(size_t)(m0 + quad * 4 + r) * 256 + f];
    }

    // LN pass 1: mean. per-lane sum over ni, butterfly over qrow (16 lanes),
    // cross-wave via lnp[0][token][wv].
    f32x4 ps;
#pragma unroll
    for (int r = 0; r < 4; r++) ps[r] = d[0][r] + d[1][r] + d[2][r] + d[3][r];
#pragma unroll
    for (int off = 1; off <= 8; off <<= 1)
#pragma unroll
        for (int r = 0; r < 4; r++) ps[r] += __shfl_xor(ps[r], off, 64);
    if (qrow == 0)
#pragma unroll
        for (int r = 0; r < 4; r++) lnp[0][quad * 4 + r][wv] = ps[r];
    __syncthreads();
    float mu[4];
#pragma unroll
    for (int r = 0; r < 4; r++) {
        const int t = quad * 4 + r;
        mu[r] = (lnp[0][t][0] + lnp[0][t][1] + lnp[0][t][2] + lnp[0][t][3]) * (1.f / 256.f);
    }

    // LN pass 2: variance (two-pass, centered)
#pragma unroll
    for (int r = 0; r < 4; r++) {
        float a0 = d[0][r] - mu[r], a1 = d[1][r] - mu[r];
        float a2 = d[2][r] - mu[r], a3 = d[3][r] - mu[r];
        ps[r] = a0 * a0 + a1 * a1 + a2 * a2 + a3 * a3;
    }
#pragma unroll
    for (int off = 1; off <= 8; off <<= 1)
#pragma unroll
        for (int r = 0; r < 4; r++) ps[r] += __shfl_xor(ps[r], off, 64);
    if (qrow == 0)
#pragma unroll
        for (int r = 0; r < 4; r++) lnp[1][quad * 4 + r][wv] = ps[r];
    __syncthreads();
    float rsv[4];
#pragma unroll
    for (int r = 0; r < 4; r++) {
        const int t = quad * 4 + r;
        float v = (lnp[1][t][0] + lnp[1][t][1] + lnp[1][t][2] + lnp[1][t][3]) * (1.f / 256.f);
        rsv[r] = rsqrtf(v + 1e-5f);
    }

    // write: out = (d - mu) * rs * g + be
#pragma unroll
    for (int ni = 0; ni < 4; ni++) {
        const int f = wv * 64 + ni * 16 + qrow;
        const float gg = g[f];
        const float bb = be[f];
#pragma unroll
        for (int r = 0; r < 4; r++) {
            const size_t idx = (size_t)(m0 + quad * 4 + r) * 256 + f;
            float o = (d[ni][r] - mu[r]) * rsv[r] * gg + bb;
            out[idx] = o;
            if (OBF) outb[idx] = (__bf16)o;
        }
    }
}

// ---------------------------------------------------------------------------
// attn_fused: 512-thread blocks.
// Blocks 0..1023: global MHA split-K x4 partials. 8 waves x 2 q-tiles x 16 q
//   = 256 q/block, 8 key-chunks of 64 keys each. P never touches LDS
//   (permlane transpose). exp2+bf16-pack via v_exp_f32 + v_cvt_pk_bf16_f32.
// Blocks 1024..1535: local window-5 MHA -> acat cols 256-511.
// ---------------------------------------------------------------------------
__global__ __launch_bounds__(512) void attn_fused(
    const __bf16* __restrict__ qkv, __bf16* __restrict__ Op,
    float* __restrict__ Lp, __bf16* __restrict__ acat)
{
    __shared__ __bf16 Kl[2][64 * 32];
    __shared__ __bf16 Vt[2][32 * 72];

    const int t = threadIdx.x;
    const int lane = t & 63;
    const int wv = t >> 6;          // 0..7

    if (blockIdx.x < 1024) {
        const int bid = blockIdx.x;
        const int sp = bid & 3;          // split-K x4
        const int qc = (bid >> 2) & 7;   // 8 chunks of 256 q
        const int h  = (bid >> 5) & 7;
        const int b  = bid >> 8;
        const int bS = b * Ss;
        const int q0 = qc * 256;

        const int qrow = lane & 15;
        const int quad = lane >> 4;
        const float cQ = 1.4426950408889634f * 0.17677669529663687f; // log2e/sqrt(32)

        bf16x8 qf[2];
#pragma unroll
        for (int tl = 0; tl < 2; tl++) {
            bf16x8 qraw = *(const bf16x8*)(qkv +
                (size_t)(bS + q0 + wv * 32 + tl * 16 + qrow) * QSTR + h * 32 + quad * 8);
#pragma unroll
            for (int i = 0; i < 8; i++) qf[tl][i] = (__bf16)((float)qraw[i] * cQ);
        }
        bf16x8 ones;
#pragma unroll
        for (int i = 0; i < 8; i++) ones[i] = (__bf16)1.0f;

        f32x4 o0[2], o1[2], lac[2];
#pragma unroll
        for (int tl = 0; tl < 2; tl++) {
            o0[tl] = {0.f, 0.f, 0.f, 0.f};
            o1[tl] = {0.f, 0.f, 0.f, 0.f};
            lac[tl] = {0.f, 0.f, 0.f, 0.f};
        }
        const f32x4 z = {0.f, 0.f, 0.f, 0.f};

        const int kc_c = wv * 64 + lane;
        const int kkey = kc_c >> 2, kdg = kc_c & 3;
        const int vkey = t & 63, vq = t >> 6;   // V: key, dim group of 4
        const int kc0 = sp * 8;                 // 8 chunks per split

        // prologue: prefetch chunk 0 (V into regs, K via glds into Kl[0])
        bf16x4 vreg = *(const bf16x4*)(qkv +
            (size_t)(bS + kc0 * 64 + vkey) * QSTR + 512 + h * 32 + vq * 4);
        if (wv < 4)
            glds16(qkv + (size_t)(bS + kc0 * 64 + kkey) * QSTR + 256 + h * 32 + kdg * 8,
                   &Kl[0][wv * 512]);

        for (int i = 0; i < 8; i++) {
            const int cur = i & 1;
#pragma unroll
            for (int e = 0; e < 4; e++) Vt[cur][(vq * 4 + e) * 72 + vkey] = vreg[e];
            __syncthreads();
            const int nx = (i < 7) ? (kc0 + i + 1) : (kc0 + 7);
            vreg = *(const bf16x4*)(qkv +
                (size_t)(bS + nx * 64 + vkey) * QSTR + 512 + h * 32 + vq * 4);
            if (i < 7 && wv < 4)
                glds16(qkv + (size_t)(bS + nx * 64 + kkey) * QSTR + 256 + h * 32 + kdg * 8,
                       &Kl[1 - cur][wv * 512]);

            // shared K/V fragments, read once, used by both q-tiles
            bf16x8 kf[4];
#pragma unroll
            for (int kg = 0; kg < 4; kg++)
                kf[kg] = *(const bf16x8*)&Kl[cur][(kg * 16 + qrow) * 32 + quad * 8];
            bf16x8 vf00 = *(const bf16x8*)&Vt[cur][qrow * 72 + quad * 8];
            bf16x8 vf01 = *(const bf16x8*)&Vt[cur][qrow * 72 + 32 + quad * 8];
            bf16x8 vf10 = *(const bf16x8*)&Vt[cur][(16 + qrow) * 72 + quad * 8];
            bf16x8 vf11 = *(const bf16x8*)&Vt[cur][(16 + qrow) * 72 + 32 + quad * 8];

#pragma unroll
            for (int tl = 0; tl < 2; tl++) {
                f32x4 s[4];
#pragma unroll
                for (int kg = 0; kg < 4; kg++)
                    s[kg] = __builtin_amdgcn_mfma_f32_16x16x32_bf16(
                        kf[kg], qf[tl], z, 0, 0, 0);
                unsigned int R[4][2];
#pragma unroll
                for (int kg = 0; kg < 4; kg++) {
                    R[kg][0] = exp2_pk(s[kg][0], s[kg][1]);
                    R[kg][1] = exp2_pk(s[kg][2], s[kg][3]);
                }
                xpose4(R[0][0], R[1][0]);
                xpose4(R[0][1], R[1][1]);
                xpose4(R[2][0], R[3][0]);
                xpose4(R[2][1], R[3][1]);
                uint4v p0u = {R[0][0], R[0][1], R[1][0], R[1][1]};
                uint4v p1u = {R[2][0], R[2][1], R[3][0], R[3][1]};
                bf16x8 pf0 = __builtin_bit_cast(bf16x8, p0u);
                bf16x8 pf1 = __builtin_bit_cast(bf16x8, p1u);

                o0[tl] = __builtin_amdgcn_mfma_f32_16x16x32_bf16(vf00, pf0, o0[tl], 0, 0, 0);
                o1[tl] = __builtin_amdgcn_mfma_f32_16x16x32_bf16(vf10, pf0, o1[tl], 0, 0, 0);
                lac[tl] = __builtin_amdgcn_mfma_f32_16x16x32_bf16(ones, pf0, lac[tl], 0, 0, 0);
                o0[tl] = __builtin_amdgcn_mfma_f32_16x16x32_bf16(vf01, pf1, o0[tl], 0, 0, 0);
                o1[tl] = __builtin_amdgcn_mfma_f32_16x16x32_bf16(vf11, pf1, o1[tl], 0, 0, 0);
                lac[tl] = __builtin_amdgcn_mfma_f32_16x16x32_bf16(ones, pf1, lac[tl], 0, 0, 0);
            }
        }

#pragma unroll
        for (int tl = 0; tl < 2; tl++) {
            const int gid = (b * 8 + h) * 2048 + q0 + wv * 32 + tl * 16 + qrow;
            __bf16* po = Op + (size_t)sp * 2097152 + (size_t)gid * 32;
            bf16x4 w0, w1;
#pragma unroll
            for (int r = 0; r < 4; r++) {
                w0[r] = (__bf16)o0[tl][r];
                w1[r] = (__bf16)o1[tl][r];
            }
            *(bf16x4*)&po[quad * 4]      = w0;
            *(bf16x4*)&po[16 + quad * 4] = w1;
            if (quad == 0) Lp[sp * 65536 + gid] = lac[tl][0];
        }
    } else {
        // local window-5 attention: 8 lanes per (b,s,h) row, 8 rows per wave
        const int w = (blockIdx.x - 1024) * 8 + wv;  // 0..4095
        const int g = lane >> 3;                      // row-in-wave 0..7
        const int l8 = lane & 7;                      // dim-group (8 bf16)
        const int R = w * 8 + g;                      // 0..32767
        const int h = R & 3;
        const int s = (R >> 2) & 2047;
        const int b = R >> 13;

        float qv[8];
        {
            bf16x8 q8 = *(const bf16x8*)&qkv[(size_t)(b * Ss + s) * QSTR + 768 + h * 64 + l8 * 8];
#pragma unroll
            for (int e = 0; e < 8; e++) qv[e] = (float)q8[e];
        }

        float sc[5];
        bf16x8 v8[5];
#pragma unroll
        for (int j = 0; j < 5; j++) {
            int pos = s + j - 2;
            bool valid = (pos >= 0) && (pos < Ss);
            int cpos = valid ? pos : 0;
            const size_t rb = (size_t)(b * Ss + cpos) * QSTR;
            bf16x8 k8 = *(const bf16x8*)&qkv[rb + 1024 + h * 64 + l8 * 8];
            v8[j]     = *(const bf16x8*)&qkv[rb + 1280 + h * 64 + l8 * 8];
            float p = 0.f;
#pragma unroll
            for (int e = 0; e < 8; e++) p += qv[e] * (float)k8[e];
            p += __shfl_xor(p, 1, 64);
            p += __shfl_xor(p, 2, 64);
            p += __shfl_xor(p, 4, 64);
            sc[j] = valid ? p * 0.125f : -1e30f;
        }
        float m = sc[0];
#pragma unroll
        for (int j = 1; j < 5; j++) m = fmaxf(m, sc[j]);
        float l = 0.f;
        float o[8];
#pragma unroll
        for (int e = 0; e < 8; e++) o[e] = 0.f;
#pragma unroll
        for (int j = 0; j < 5; j++) {
            float pe = __builtin_amdgcn_exp2f((sc[j] - m) * 1.4426950408889634f);
            l += pe;
#pragma unroll
            for (int e = 0; e < 8; e++) o[e] += pe * (float)v8[j][e];
        }
        const float li = 1.f / l;
        bf16x8 r;
#pragma unroll
        for (int e = 0; e < 8; e++) r[e] = (__bf16)(o[e] * li);
        *(bf16x8*)&acat[(size_t)(b * Ss + s) * 512 + 256 + h * 64 + l8 * 8] = r;
    }
}

// ---------------------------------------------------------------------------
// attn_combine: 4 bf16 split partials -> acat cols 0-255.
// ---------------------------------------------------------------------------
__global__ __launch_bounds__(256) void attn_combine(
    const __bf16* __restrict__ Op, const float* __restrict__ Lp,
    __bf16* __restrict__ acat)
{
    const int t = blockIdx.x * 256 + threadIdx.x;   // 0 .. 524287
    const int gid = t >> 3;
    const int dg = t & 7;
    const int b = gid >> 14;
    const int h = (gid >> 11) & 7;
    const int q = gid & 2047;

    const float li = 1.f / (Lp[gid] + Lp[65536 + gid] +
                            Lp[131072 + gid] + Lp[196608 + gid]);
    const __bf16* base = Op + (size_t)gid * 32 + dg * 4;
    bf16x4 a0 = *(const bf16x4*)&base[0];
    bf16x4 a1 = *(const bf16x4*)&base[2097152];
    bf16x4 a2 = *(const bf16x4*)&base[4194304];
    bf16x4 a3 = *(const bf16x4*)&base[6291456];
    bf16x4 r;
#pragma unroll
    for (int i = 0; i < 4; i++)
        r[i] = (__bf16)(((float)a0[i] + (float)a1[i] +
                         (float)a2[i] + (float)a3[i]) * li);
    *(bf16x4*)&acat[(size_t)(b * Ss + q) * 512 + h * 32 + dg * 4] = r;
}

// ---------------------------------------------------------------------------
extern "C" void kernel_launch(void* const* d_in, const int* in_sizes, int n_in,
                              void* d_out, int out_size, void* d_ws, size_t ws_size,
                              hipStream_t stream)
{
    const float* x      = (const float*)d_in[0];
    const float* g_in_w = (const float*)d_in[1];
    const float* g_in_b = (const float*)d_in[2];
    const float* g_out_w= (const float*)d_in[3];
    const float* g_out_b= (const float*)d_in[4];
    const float* t_in_w = (const float*)d_in[5];
    const float* t_in_b = (const float*)d_in[6];
    const float* t_out_w= (const float*)d_in[7];
    const float* t_out_b= (const float*)d_in[8];
    const float* fus_w1 = (const float*)d_in[9];
    const float* fus_b1 = (const float*)d_in[10];
    const float* fus_w2 = (const float*)d_in[11];
    const float* fus_b2 = (const float*)d_in[12];
    const float* ffn_w1 = (const float*)d_in[13];
    const float* ffn_b1 = (const float*)d_in[14];
    const float* ffn_w2 = (const float*)d_in[15];
    const float* ffn_b2 = (const float*)d_in[16];
    const float* gn_g   = (const float*)d_in[17];
    const float* gn_b   = (const float*)d_in[18];
    const float* fn_g   = (const float*)d_in[19];
    const float* fn_b   = (const float*)d_in[20];
    float* out = (float*)d_out;
    float* ws  = (float*)d_ws;

    // ws layout in f32 slots
    __bf16* xb     = (__bf16*)(ws);                 // [0, 1048576)
    __bf16* wb     = (__bf16*)(ws + 1048576);       // [1048576, 1638400)
    __bf16* qkvgl  = (__bf16*)(ws + 1638400);       // [1638400, 7929856)  8192x1536
    __bf16* acat   = (__bf16*)(ws + 7929856);       // [7929856, 10027008) 8192x512
    __bf16* fcomb  = (__bf16*)(ws + 10027008);      // [10027008, 12124160) 8192x512
    __bf16* h1     = (__bf16*)(ws + 12124160);      // [12124160, 14221312) 8192x512
    float*  x2     = ws + 16318464;                 // [16318464, 18415616) fp32
    __bf16* x2b    = (__bf16*)(ws + 18415616);      // [18415616, 19464192)
    __bf16* h2     = h1;                            // reuse
    // attention partials: live only between attn_fused and attn_combine.
    __bf16* Op = (__bf16*)(ws + 10027008);          // 4x65536x32 bf16 over fcomb+h1
    float*  Lp = ws + 18415616;                     // 4x65536 fp32 over x2b

    __bf16* w_gin  = wb;              // [1536x256] combined (g rows 0-767, t 768-1535)
    __bf16* w_gout = wb + 393216;
    __bf16* w_tout = wb + 458752;
    __bf16* w_f1   = wb + 524288;
    __bf16* w_f2   = wb + 786432;
    __bf16* w_n1   = wb + 917504;
    __bf16* w_n2   = wb + 1048576;

    CvtArgs ca;
    ca.src[0] = x;      ca.dst[0] = xb;
    ca.src[1] = g_in_w; ca.dst[1] = w_gin;
    ca.src[2] = t_in_w; ca.dst[2] = w_gin + 196608;
    ca.src[3] = g_out_w;ca.dst[3] = w_gout;
    ca.src[4] = t_out_w;ca.dst[4] = w_tout;
    ca.src[5] = fus_w1; ca.dst[5] = w_f1;
    ca.src[6] = fus_w2; ca.dst[6] = w_f2;
    ca.src[7] = ffn_w1; ca.dst[7] = w_n1;
    ca.src[8] = ffn_w2; ca.dst[8] = w_n2;
    int st[10] = {0, 1024, 1120, 1216, 1248, 1280, 1408, 1472, 1536, 1600};
    for (int i = 0; i < 10; i++) ca.start[i] = st[i];

    convert_all<<<dim3(1600), 256, 0, stream>>>(ca);

    // Combined QKV projection: M=8192, N=1536, K=256 -> qkvgl (128x128 tiles)
    gemm128<<<dim3(12, 64), 256, 0, stream>>>(
        xb, w_gin, g_in_b, t_in_b, 768, qkvgl, 256, QSTR);
    // Global attention partials split-K x4 (blocks 0-1023) + local (1024-1535)
    attn_fused<<<dim3(1536), 512, 0, stream>>>(qkvgl, Op, Lp, acat);
    // Combine partials -> acat cols 0-255
    attn_combine<<<dim3(2048), 256, 0, stream>>>(Op, Lp, acat);
    // Fused output projections (both halves in one launch) into fcomb
    gemm_mid<false, true><<<dim3(8, 128), 256, 0, stream>>>(
        acat, w_gout, g_out_b, w_tout, t_out_b, 4, 256, 256, fcomb, 512, 256, 512);
    // Fusion MLP layer 1
    gemm_mid<true,  true><<<dim3(8, 128), 256, 0, stream>>>(
        fcomb, w_f1, fus_b1, w_f1, fus_b1, 1 << 30, 0, 0, h1, 512, 512, 512);
    // Fusion MLP layer 2 + residual(x) + LN1 -> x2 (fp32) and x2b (bf16)
    gemm_ln<true><<<dim3(512), 256, 0, stream>>>(
        h1, w_f2, fus_b2, x, gn_g, gn_b, x2, x2b);
    // FFN layer 1
    gemm_mid<true,  true><<<dim3(8, 128), 256, 0, stream>>>(
        x2b, w_n1, ffn_b1, w_n1, ffn_b1, 1 << 30, 0, 0, h2, 256, 256, 512);
    // FFN layer 2 + residual(x2) + LN2 -> out
    gemm_ln<false><<<dim3(512), 256, 0, stream>>>(
        h2, w_n2, ffn_b2, x2, fn_g, fn_b, out, nullptr);
}